// Round 8
// baseline (369.380 us; speedup 1.0000x reference)
//
#include <hip/hip_runtime.h>
#include <hip/hip_bf16.h>

#define F_IN 256
#define HID  128
#define SSUB 50
#define KFIN 6400   // SSUB * HID
#define NPB  256    // nodes per partition bucket (power of 2: bucket = dst >> 8)

typedef __attribute__((ext_vector_type(4))) float f32x4;
typedef __attribute__((ext_vector_type(8))) short bf16x8;

__device__ __forceinline__ void split_bf16(float v, short& hi, short& lo) {
    __hip_bfloat16 h = __float2bfloat16(v);
    float hf = __bfloat162float(h);
    __hip_bfloat16 l = __float2bfloat16(v - hf);   // exact residual, then RNE to bf16
    hi = __builtin_bit_cast(short, h);
    lo = __builtin_bit_cast(short, l);
}

__device__ __forceinline__ float bf2f(unsigned short u) {
    return __builtin_bit_cast(float, (unsigned)u << 16);
}

// ---------------- CSR build ----------------

__global__ void k_zero_int(int* __restrict__ p, int n) {
    int i = blockIdx.x * blockDim.x + threadIdx.x;
    if (i < n) p[i] = 0;
}

// coarse histogram over 196 buckets (dst>>8), LDS-aggregated:
// 1.6M edges -> ~76K global atomics on 256 addresses (vs 1.6M on 50K).
__global__ __launch_bounds__(256) void k_bhist(const int* __restrict__ dst,
                                               int* __restrict__ bcnt, int E) {
    __shared__ int lcnt[256];
    int tid = threadIdx.x;
    lcnt[tid] = 0;
    __syncthreads();
    int n4 = E >> 2;
    int stride = gridDim.x * 256;
    for (int i = blockIdx.x * 256 + tid; i < n4; i += stride) {
        int4 d = ((const int4*)dst)[i];
        atomicAdd(&lcnt[d.x >> 8], 1);
        atomicAdd(&lcnt[d.y >> 8], 1);
        atomicAdd(&lcnt[d.z >> 8], 1);
        atomicAdd(&lcnt[d.w >> 8], 1);
    }
    if (blockIdx.x == 0) {
        for (int e = (n4 << 2) + tid; e < E; e += 256)
            atomicAdd(&lcnt[dst[e] >> 8], 1);
    }
    __syncthreads();
    if (lcnt[tid]) atomicAdd(&bcnt[tid], lcnt[tid]);
}

// exclusive scan of 256 bucket counts -> bbase[0..256]; bcursor = copy for partition
__global__ void k_bscan(const int* __restrict__ bcnt, int* __restrict__ bbase,
                        int* __restrict__ bcursor) {
    __shared__ int buf[256];
    int tid = threadIdx.x;
    int v = bcnt[tid];
    buf[tid] = v;
    __syncthreads();
    for (int off = 1; off < 256; off <<= 1) {
        int t = (tid >= off) ? buf[tid - off] : 0;
        __syncthreads();
        buf[tid] += t;
        __syncthreads();
    }
    int ex = buf[tid] - v;
    bbase[tid] = ex;
    bcursor[tid] = ex;
    if (tid == 255) bbase[256] = buf[255];
}

// ---- partition edges into coarse buckets (dst>>8), block-batched append ----
// 4096 edges per block; LDS count -> one global reservation per bucket per block ->
// append packed (src<<8 | dst&255) ints (src < 2^24). 4B/edge instead of 8B.
__global__ __launch_bounds__(256) void k_partition(const int* __restrict__ src,
                                                   const int* __restrict__ dst,
                                                   int* __restrict__ bcursor,
                                                   int* __restrict__ part, int E) {
    __shared__ int lcnt[256];
    __shared__ int lbase[256];
    int tid = threadIdx.x;
    lcnt[tid] = 0;
    __syncthreads();
    int base = blockIdx.x * 4096;
    int pp[16], rb[16];
#pragma unroll
    for (int i = 0; i < 16; ++i) {
        int e = base + i * 256 + tid;
        int pv = 0, pk = 0;
        if (e < E) {
            int s = src[e];
            int d = dst[e];
            int b = d >> 8;                     // NPB = 256
            int r = atomicAdd(&lcnt[b], 1);     // r < 4096
            pk = (r << 8) | b;
            pv = (s << 8) | (d & 255);
        }
        pp[i] = pv; rb[i] = pk;
    }
    __syncthreads();
    lbase[tid] = lcnt[tid] ? atomicAdd(&bcursor[tid], lcnt[tid]) : 0;
    __syncthreads();
#pragma unroll
    for (int i = 0; i < 16; ++i) {
        int e = base + i * 256 + tid;
        if (e < E) {
            int b = rb[i] & 255;
            int r = rb[i] >> 8;
            part[(size_t)(lbase[b] + r)] = pp[i];
        }
    }
}

// ---- per-bucket counting sort: count -> local scan -> row_ptr/dinv -> scatter ----
// One block per bucket, 512 threads (196 blocks < 256 CUs: whole CU per block, so
// more waves = more MLP for the latency-bound gather/scatter loops). Zero global
// atomics; csr writes confined to the bucket's ~32KB window (L2-coalesced).
__global__ __launch_bounds__(512) void k_bucket_sort(const int* __restrict__ part,
                                                     const int* __restrict__ bbase,
                                                     int* __restrict__ row_ptr,
                                                     float* __restrict__ dinv,
                                                     int* __restrict__ csr_src,
                                                     int N, int E) {
    __shared__ int lcnt[256];
    __shared__ int lcur[256];
    __shared__ int sbuf[256];
    int tid = threadIdx.x;
    int b = blockIdx.x;
    int beg = bbase[b], end = bbase[b + 1];
    if (tid < 256) lcnt[tid] = 0;
    __syncthreads();
    for (int k = beg + tid; k < end; k += 512)
        atomicAdd(&lcnt[part[k] & (NPB - 1)], 1);
    __syncthreads();
    int v = (tid < 256) ? lcnt[tid] : 0;
    if (tid < 256) sbuf[tid] = v;
    __syncthreads();
    for (int off = 1; off < 256; off <<= 1) {
        int t = (tid >= off && tid < 256) ? sbuf[tid - off] : 0;
        __syncthreads();
        if (tid < 256) sbuf[tid] += t;
        __syncthreads();
    }
    if (tid < 256) {
        int loff = sbuf[tid] - v;        // exclusive within-bucket offset
        lcur[tid] = beg + loff;
        int node = b * NPB + tid;
        if (node < N) {
            row_ptr[node] = beg + loff;
            dinv[node] = rsqrtf((float)(v + 1));   // +1 self loop
        }
        if (node == 0) row_ptr[N] = E;
    }
    __syncthreads();
    for (int k = beg + tid; k < end; k += 512) {
        int p = part[k];
        int pos = atomicAdd(&lcur[p & (NPB - 1)], 1);
        csr_src[pos] = p >> 8;
    }
}

// ---------------- W split: fp32 (K x 128) -> fragment-linear bf16 hi/lo ----------------
template<int K>
__global__ void k_wsplit(const float* __restrict__ W, short* __restrict__ Bf) {
    int t = blockIdx.x * 256 + threadIdx.x;
    if (t >= K * HID) return;
    int k = t >> 7, n = t & 127;
    short hi, lo;
    split_bf16(W[t], hi, lo);
    int kc = k >> 5, ko = k & 31;
    int quad = ko >> 3, j = ko & 7;
    int nt = n >> 4, nc = n & 15;
    int lane = (quad << 4) | nc;
    size_t idx = (((size_t)(kc * 8 + nt)) * 64 + lane) * 8 + j;
    Bf[idx] = hi;
    Bf[(size_t)K * HID + idx] = lo;
}

// ---------------- MFMA GEMM: Cb(MxHID, bf16) = (A(MxK, fp32) @ W) * dinv[row] ----------------
// LDS-free (A has zero cross-thread reuse). 32 rows per wave (2 m-fragments):
// B fragments loaded once per kc into registers and reused across both m-frags,
// halving B L2-traffic (K=256: 400->200 MB) and B vmem instruction count.
// Block = 2 waves = 64 rows.
template<int K>
__global__ __launch_bounds__(128) void k_gemm_mfma(const float* __restrict__ A,
                                                   const short* __restrict__ Bf,
                                                   const float* __restrict__ dinv,
                                                   unsigned short* __restrict__ Cb, int M) {
    constexpr int KC = K / 32;
    int tid = threadIdx.x;
    int base = blockIdx.x * 64;
    int lane = tid & 63;
    int w = tid >> 6;
    int quad = lane >> 4;
    int row0 = base + w * 32 + (lane & 15);       // f=0 row
    const float* arow0 = A + (size_t)row0 * K;
    const float* arow1 = arow0 + (size_t)16 * K;  // f=1 row = row0 + 16
    bool valid0 = (row0 < M);
    bool valid1 = (row0 + 16 < M);
    f32x4 acc[2][8] = {};
    const bf16x8* BfH = (const bf16x8*)Bf;
    const bf16x8* BfL = (const bf16x8*)(Bf + (size_t)K * HID);

    for (int kc = 0; kc < KC; ++kc) {
        // B once per kc, shared by both m-fragments
        bf16x8 bh[8], bl[8];
        size_t boff = ((size_t)kc * 8) * 64 + lane;
#pragma unroll
        for (int nt = 0; nt < 8; ++nt) {
            bh[nt] = BfH[boff + (size_t)nt * 64];
            bl[nt] = BfL[boff + (size_t)nt * 64];
        }
#pragma unroll
        for (int f = 0; f < 2; ++f) {
            const float* ar = f ? arow1 : arow0;
            bool valid = f ? valid1 : valid0;
            f32x4 a0 = {0.f, 0.f, 0.f, 0.f};
            f32x4 a1 = {0.f, 0.f, 0.f, 0.f};
            if (valid) {
                a0 = *(const f32x4*)(ar + kc * 32 + quad * 8);
                a1 = *(const f32x4*)(ar + kc * 32 + quad * 8 + 4);
            }
            bf16x8 ahi, alo;
#pragma unroll
            for (int j2 = 0; j2 < 4; ++j2) {
                short hi, lo;
                split_bf16(a0[j2], hi, lo);
                ahi[j2] = hi; alo[j2] = lo;
                split_bf16(a1[j2], hi, lo);
                ahi[4 + j2] = hi; alo[4 + j2] = lo;
            }
#pragma unroll
            for (int nt = 0; nt < 8; ++nt)
                acc[f][nt] = __builtin_amdgcn_mfma_f32_16x16x32_bf16(ahi, bh[nt], acc[f][nt], 0, 0, 0);
#pragma unroll
            for (int nt = 0; nt < 8; ++nt)
                acc[f][nt] = __builtin_amdgcn_mfma_f32_16x16x32_bf16(alo, bh[nt], acc[f][nt], 0, 0, 0);
#pragma unroll
            for (int nt = 0; nt < 8; ++nt)
                acc[f][nt] = __builtin_amdgcn_mfma_f32_16x16x32_bf16(ahi, bl[nt], acc[f][nt], 0, 0, 0);
        }
    }

    // epilogue: scale row by dinv[m], quantize to bf16 (RNE)
    int ncol = lane & 15;
#pragma unroll
    for (int f = 0; f < 2; ++f) {
        int mbase = base + w * 32 + f * 16 + quad * 4;
        float dsc[4];
#pragma unroll
        for (int r = 0; r < 4; ++r)
            dsc[r] = (mbase + r < M) ? dinv[mbase + r] : 0.f;
#pragma unroll
        for (int nt = 0; nt < 8; ++nt) {
#pragma unroll
            for (int r = 0; r < 4; ++r) {
                int m = mbase + r;
                if (m < M) {
                    __hip_bfloat16 b = __float2bfloat16(acc[f][nt][r] * dsc[r]);
                    Cb[(size_t)m * HID + nt * 16 + ncol] = __builtin_bit_cast(unsigned short, b);
                }
            }
        }
    }
}

// ---------------- CSR aggregation over bf16 gather buffer ----------------
// Wave-per-node: lane = e4*16 + t; e4 in [0,4) processes every 4th edge,
// t in [0,16) owns features [t*8, t*8+8) via one 16B bf16x8 load per edge.
// out[n] = dinv[n] * (hs[n] + sum_in hs[src]) + bias  (+relu), fp32 accumulate/out
__global__ __launch_bounds__(256) void k_agg(const unsigned short* __restrict__ hs,
                                             const int* __restrict__ row_ptr,
                                             const int* __restrict__ csr_src,
                                             const float* __restrict__ dinv,
                                             const float* __restrict__ bias,
                                             float* __restrict__ out, int relu, int M) {
    int n = blockIdx.x * 4 + (threadIdx.x >> 6);   // one wave per node
    if (n >= M) return;
    int lane = threadIdx.x & 63;
    int e4 = lane >> 4;       // edge sub-group 0..3
    int t  = lane & 15;       // feature group: 8 bf16 = 16B per lane

    int beg = row_ptr[n];
    int end = row_ptr[n + 1];

    float acc[8] = {0.f, 0.f, 0.f, 0.f, 0.f, 0.f, 0.f, 0.f};
    if (e4 == 0) {
        // self loop (hs pre-scaled by dinv[src])
        bf16x8 v = *(const bf16x8*)(hs + (size_t)n * HID + t * 8);
#pragma unroll
        for (int j = 0; j < 8; ++j) acc[j] = bf2f((unsigned short)v[j]);
    }

    int k = beg + e4;
    for (; k + 12 < end; k += 16) {
        int s0 = csr_src[k];
        int s1 = csr_src[k + 4];
        int s2 = csr_src[k + 8];
        int s3 = csr_src[k + 12];
        bf16x8 v0 = *(const bf16x8*)(hs + (size_t)s0 * HID + t * 8);
        bf16x8 v1 = *(const bf16x8*)(hs + (size_t)s1 * HID + t * 8);
        bf16x8 v2 = *(const bf16x8*)(hs + (size_t)s2 * HID + t * 8);
        bf16x8 v3 = *(const bf16x8*)(hs + (size_t)s3 * HID + t * 8);
#pragma unroll
        for (int j = 0; j < 8; ++j)
            acc[j] += (bf2f((unsigned short)v0[j]) + bf2f((unsigned short)v1[j]))
                    + (bf2f((unsigned short)v2[j]) + bf2f((unsigned short)v3[j]));
    }
    for (; k + 4 < end; k += 8) {
        int s0 = csr_src[k];
        int s1 = csr_src[k + 4];
        bf16x8 v0 = *(const bf16x8*)(hs + (size_t)s0 * HID + t * 8);
        bf16x8 v1 = *(const bf16x8*)(hs + (size_t)s1 * HID + t * 8);
#pragma unroll
        for (int j = 0; j < 8; ++j)
            acc[j] += bf2f((unsigned short)v0[j]) + bf2f((unsigned short)v1[j]);
    }
    if (k < end) {
        int s0 = csr_src[k];
        bf16x8 v0 = *(const bf16x8*)(hs + (size_t)s0 * HID + t * 8);
#pragma unroll
        for (int j = 0; j < 8; ++j)
            acc[j] += bf2f((unsigned short)v0[j]);
    }

    // reduce the 4 e4-groups (lanes differing in bits 4,5)
#pragma unroll
    for (int j = 0; j < 8; ++j) acc[j] += __shfl_xor(acc[j], 16, 64);
#pragma unroll
    for (int j = 0; j < 8; ++j) acc[j] += __shfl_xor(acc[j], 32, 64);

    if (e4 == 0) {
        float d = dinv[n];
        f32x4 o0, o1;
#pragma unroll
        for (int j = 0; j < 4; ++j) {
            float a = acc[j] * d + bias[t * 8 + j];
            if (relu) a = fmaxf(a, 0.f);
            o0[j] = a;
        }
#pragma unroll
        for (int j = 0; j < 4; ++j) {
            float a = acc[4 + j] * d + bias[t * 8 + 4 + j];
            if (relu) a = fmaxf(a, 0.f);
            o1[j] = a;
        }
        *(f32x4*)(out + (size_t)n * HID + t * 8)     = o0;
        *(f32x4*)(out + (size_t)n * HID + t * 8 + 4) = o1;
    }
}

// ---------------- final linear: out = pooled @ Wl + bl (MFMA, split-K) ----------------
__global__ void k_final_init(const float* __restrict__ bl, float* __restrict__ out, int total) {
    int t = blockIdx.x * blockDim.x + threadIdx.x;
    if (t < total) out[t] = bl[t & (HID - 1)];
}

// 256 threads (4 waves), BM=128 M-rows per block (wave w owns rows w*32..w*32+31
// as 2 MFMA m-fragments), K-slice KS per blockIdx.y, LDS tile TILE cols at a time.
// B traffic = nx * 3.27MB = 26MB regardless of split-K depth. KS=256 -> 25
// K-slices -> 200 blocks / 800 waves for latency hiding.
template<int KS, int TILE>
__global__ __launch_bounds__(256) void k_final_mfma(const float* __restrict__ emb,
                                                    const short* __restrict__ Bf,
                                                    float* __restrict__ out, int M) {
    constexpr int BM = 128;
    constexpr int LDA = TILE + 4;
    __shared__ float As[BM * LDA];
    int tid = threadIdx.x;
    int g0 = blockIdx.x * BM;
    int k0 = blockIdx.y * KS;
    int lane = tid & 63;
    int w = tid >> 6;
    int quad = lane >> 4;
    f32x4 acc[2][8] = {};
    const bf16x8* BfH = (const bf16x8*)Bf;
    const bf16x8* BfL = (const bf16x8*)(Bf + (size_t)KFIN * HID);

    for (int t = 0; t < KS / TILE; ++t) {
        __syncthreads();
        constexpr int ITERS = (BM * (TILE / 4)) / 256;
#pragma unroll
        for (int i = 0; i < ITERS; ++i) {
            int f4 = tid + i * 256;
            int row = f4 / (TILE / 4);
            int c4 = f4 % (TILE / 4);
            f32x4 v = {0.f, 0.f, 0.f, 0.f};
            int m = g0 + row;
            if (m < M) v = *(const f32x4*)(emb + (size_t)m * KFIN + k0 + t * TILE + c4 * 4);
            *(f32x4*)(&As[row * LDA + c4 * 4]) = v;
        }
        __syncthreads();
        for (int kc = 0; kc < TILE / 32; ++kc) {
            int kcg = (k0 + t * TILE) / 32 + kc;
            bf16x8 bh[8], bl[8];
            size_t boff = (size_t)kcg * 8 * 64 + lane;
#pragma unroll
            for (int nt = 0; nt < 8; ++nt) {
                bh[nt] = BfH[boff + (size_t)nt * 64];
                bl[nt] = BfL[boff + (size_t)nt * 64];
            }
#pragma unroll
            for (int f = 0; f < 2; ++f) {
                int mrow = w * 32 + f * 16 + (lane & 15);
                const float* ap = &As[mrow * LDA + kc * 32 + quad * 8];
                f32x4 a0 = *(const f32x4*)ap;
                f32x4 a1 = *(const f32x4*)(ap + 4);
                bf16x8 ahi, alo;
#pragma unroll
                for (int j2 = 0; j2 < 4; ++j2) {
                    short hi, lo;
                    split_bf16(a0[j2], hi, lo);
                    ahi[j2] = hi; alo[j2] = lo;
                    split_bf16(a1[j2], hi, lo);
                    ahi[4 + j2] = hi; alo[4 + j2] = lo;
                }
#pragma unroll
                for (int nt = 0; nt < 8; ++nt) {
                    acc[f][nt] = __builtin_amdgcn_mfma_f32_16x16x32_bf16(ahi, bh[nt], acc[f][nt], 0, 0, 0);
                    acc[f][nt] = __builtin_amdgcn_mfma_f32_16x16x32_bf16(alo, bh[nt], acc[f][nt], 0, 0, 0);
                    acc[f][nt] = __builtin_amdgcn_mfma_f32_16x16x32_bf16(ahi, bl[nt], acc[f][nt], 0, 0, 0);
                }
            }
        }
    }

    int ncol = lane & 15;
#pragma unroll
    for (int f = 0; f < 2; ++f) {
        int mbase = g0 + w * 32 + f * 16 + quad * 4;
#pragma unroll
        for (int nt = 0; nt < 8; ++nt) {
#pragma unroll
            for (int r = 0; r < 4; ++r) {
                int m = mbase + r;
                if (m < M) atomicAdd(&out[(size_t)m * HID + nt * 16 + ncol], acc[f][nt][r]);
            }
        }
    }
}

extern "C" void kernel_launch(void* const* d_in, const int* in_sizes, int n_in,
                              void* d_out, int out_size, void* d_ws, size_t ws_size,
                              hipStream_t stream) {
    const float* x  = (const float*)d_in[0];
    const float* W1 = (const float*)d_in[1];
    const float* b1 = (const float*)d_in[2];
    const float* W2 = (const float*)d_in[3];
    const float* b2 = (const float*)d_in[4];
    const float* Wl = (const float*)d_in[5];
    const float* bl = (const float*)d_in[6];
    const int* edge = (const int*)d_in[7];

    const int N = in_sizes[0] / F_IN;       // 50000
    const int E = in_sizes[7] / 2;          // 1600000
    const int G = N / SSUB;                 // 1000
    const int NH = N * HID;
    const int nbkt = (N + NPB - 1) / NPB;   // 196 coarse buckets

    const int* src = edge;
    const int* dst = edge + E;

    // workspace layout
    char* ws = (char*)d_ws;
    float* dinv    = (float*)ws;                 ws += (size_t)N * 4;
    int*   row_ptr = (int*)ws;                   ws += (size_t)(N + 64) * 4;
    int*   bcnt    = (int*)ws;                   ws += (size_t)256 * 4;
    int*   bbase   = (int*)ws;                   ws += (size_t)320 * 4;
    int*   bcursor = (int*)ws;                   ws += (size_t)256 * 4;
    int*   csr_src = (int*)ws;                   ws += (size_t)E * 4;
    int*   part    = (int*)ws;                   ws += (size_t)E * 4;   // packed (src<<8|dst&255)
    unsigned short* hs0 = (unsigned short*)ws;   ws += (size_t)NH * 2;  // bf16 gather buf L1
    unsigned short* hs1 = (unsigned short*)ws;   ws += (size_t)NH * 2;  // bf16 gather buf L2
    float* h       = (float*)ws;                 ws += (size_t)NH * 4;  // fp32 relu'd hidden
    short* Bf1     = (short*)ws;                 ws += (size_t)2 * F_IN * HID * 2;  // hi+lo bf16
    short* Bf2     = (short*)ws;                 ws += (size_t)2 * HID * HID * 2;
    short* Bfl     = (short*)ws;                 ws += (size_t)2 * KFIN * HID * 2;

    float* out_final = (float*)d_out;                 // G*H
    float* emb       = out_final + (size_t)G * HID;   // N*H

    // ---- CSR build (zero global atomics on N-wide arrays) ----
    k_zero_int<<<1, 256, 0, stream>>>(bcnt, 256);
    {
        int n4 = E >> 2;
        int blocks = (n4 + 255) / 256;
        k_bhist<<<blocks, 256, 0, stream>>>(dst, bcnt, E);
    }
    k_bscan<<<1, 256, 0, stream>>>(bcnt, bbase, bcursor);
    k_partition<<<(E + 4095) / 4096, 256, 0, stream>>>(src, dst, bcursor, part, E);
    k_bucket_sort<<<nbkt, 512, 0, stream>>>(part, bbase, row_ptr, dinv, csr_src, N, E);

    // ---- weight splits ----
    k_wsplit<F_IN><<<(F_IN * HID + 255) / 256, 256, 0, stream>>>(W1, Bf1);
    k_wsplit<HID ><<<(HID  * HID + 255) / 256, 256, 0, stream>>>(W2, Bf2);
    k_wsplit<KFIN><<<(KFIN * HID + 255) / 256, 256, 0, stream>>>(Wl, Bfl);

    // ---- layer 1 ----
    k_gemm_mfma<F_IN><<<(N + 63) / 64, 128, 0, stream>>>(x, Bf1, dinv, hs0, N);  // hs0 = bf16((x@W1)*dinv)
    k_agg<<<(N + 3) / 4, 256, 0, stream>>>(hs0, row_ptr, csr_src, dinv, b1, h, 1, N);

    // ---- layer 2 ----
    k_gemm_mfma<HID><<<(N + 63) / 64, 128, 0, stream>>>(h, Bf2, dinv, hs1, N);   // hs1 = bf16((h@W2)*dinv)
    k_agg<<<(N + 3) / 4, 256, 0, stream>>>(hs1, row_ptr, csr_src, dinv, b2, emb, 0, N);

    // ---- final linear (bias init + MFMA split-K accumulate, BM=128, 25 K-slices) ----
    k_final_init<<<(G * HID + 255) / 256, 256, 0, stream>>>(bl, out_final, G * HID);
    {
        dim3 grid((G + 127) / 128, KFIN / 256);   // (8, 25) = 200 blocks
        k_final_mfma<256, 32><<<grid, 256, 0, stream>>>(emb, Bfl, out_final, G);
    }
}

// Round 9
// 357.214 us; speedup vs baseline: 1.0341x; 1.0341x over previous
//
#include <hip/hip_runtime.h>
#include <hip/hip_bf16.h>

#define F_IN 256
#define HID  128
#define SSUB 50
#define KFIN 6400   // SSUB * HID
#define NPB  256    // nodes per partition bucket (power of 2: bucket = dst >> 8)
#define BSBUF 10240 // LDS edge-buffer ints for bucket_sort (mean bucket 8192, +22σ)

typedef __attribute__((ext_vector_type(4))) float f32x4;
typedef __attribute__((ext_vector_type(8))) short bf16x8;

__device__ __forceinline__ void split_bf16(float v, short& hi, short& lo) {
    __hip_bfloat16 h = __float2bfloat16(v);
    float hf = __bfloat162float(h);
    __hip_bfloat16 l = __float2bfloat16(v - hf);   // exact residual, then RNE to bf16
    hi = __builtin_bit_cast(short, h);
    lo = __builtin_bit_cast(short, l);
}

__device__ __forceinline__ float bf2f(unsigned short u) {
    return __builtin_bit_cast(float, (unsigned)u << 16);
}

// ---------------- fused prep: wsplit(W1)+wsplit(W2)+wsplit(Wl)+bhist ----------------
// All four are mutually independent; fusing packs complementary profiles
// (bhist = atomic/latency-bound, wsplit = VALU/write-bound) into one dispatch.

template<int K>
__device__ __forceinline__ void wsplit_body(const float* __restrict__ W,
                                            short* __restrict__ Bf, int blk) {
    int t = blk * 256 + threadIdx.x;
    if (t >= K * HID) return;
    int k = t >> 7, n = t & 127;
    short hi, lo;
    split_bf16(W[t], hi, lo);
    int kc = k >> 5, ko = k & 31;
    int quad = ko >> 3, j = ko & 7;
    int nt = n >> 4, nc = n & 15;
    int lane = (quad << 4) | nc;
    size_t idx = (((size_t)(kc * 8 + nt)) * 64 + lane) * 8 + j;
    Bf[idx] = hi;
    Bf[(size_t)K * HID + idx] = lo;
}

__device__ __forceinline__ void bhist_body(const int* __restrict__ dst,
                                           int* __restrict__ bcnt,
                                           int E, int blk, int nbh) {
    __shared__ int lcnt[256];
    int tid = threadIdx.x;
    lcnt[tid] = 0;
    __syncthreads();
    int n4 = E >> 2;
    int stride = nbh * 256;
    for (int i = blk * 256 + tid; i < n4; i += stride) {
        int4 d = ((const int4*)dst)[i];
        atomicAdd(&lcnt[d.x >> 8], 1);
        atomicAdd(&lcnt[d.y >> 8], 1);
        atomicAdd(&lcnt[d.z >> 8], 1);
        atomicAdd(&lcnt[d.w >> 8], 1);
    }
    if (blk == 0) {
        for (int e = (n4 << 2) + tid; e < E; e += 256)
            atomicAdd(&lcnt[dst[e] >> 8], 1);
    }
    __syncthreads();
    if (lcnt[tid]) atomicAdd(&bcnt[tid], lcnt[tid]);
}

__global__ __launch_bounds__(256) void k_prep(const float* __restrict__ W1, short* __restrict__ Bf1,
                                              const float* __restrict__ W2, short* __restrict__ Bf2,
                                              const float* __restrict__ Wl, short* __restrict__ Bfl,
                                              const int* __restrict__ dst, int* __restrict__ bcnt,
                                              int E, int nb1, int nb2, int nbl, int nbh) {
    int b = blockIdx.x;
    if (b < nb1) { wsplit_body<F_IN>(W1, Bf1, b); return; }
    b -= nb1;
    if (b < nb2) { wsplit_body<HID>(W2, Bf2, b); return; }
    b -= nb2;
    if (b < nbl) { wsplit_body<KFIN>(Wl, Bfl, b); return; }
    b -= nbl;
    bhist_body(dst, bcnt, E, b, nbh);
}

// exclusive scan of 256 bucket counts -> bbase[0..256]; bcursor = copy for partition
__global__ void k_bscan(const int* __restrict__ bcnt, int* __restrict__ bbase,
                        int* __restrict__ bcursor) {
    __shared__ int buf[256];
    int tid = threadIdx.x;
    int v = bcnt[tid];
    buf[tid] = v;
    __syncthreads();
    for (int off = 1; off < 256; off <<= 1) {
        int t = (tid >= off) ? buf[tid - off] : 0;
        __syncthreads();
        buf[tid] += t;
        __syncthreads();
    }
    int ex = buf[tid] - v;
    bbase[tid] = ex;
    bcursor[tid] = ex;
    if (tid == 255) bbase[256] = buf[255];
}

// ---- partition edges into coarse buckets (dst>>8), block-batched append ----
// 4096 edges per block; LDS count -> one global reservation per bucket per block ->
// append packed (src<<8 | dst&255) ints (src < 2^24). 4B/edge instead of 8B.
__global__ __launch_bounds__(256) void k_partition(const int* __restrict__ src,
                                                   const int* __restrict__ dst,
                                                   int* __restrict__ bcursor,
                                                   int* __restrict__ part, int E) {
    __shared__ int lcnt[256];
    __shared__ int lbase[256];
    int tid = threadIdx.x;
    lcnt[tid] = 0;
    __syncthreads();
    int base = blockIdx.x * 4096;
    int pp[16], rb[16];
#pragma unroll
    for (int i = 0; i < 16; ++i) {
        int e = base + i * 256 + tid;
        int pv = 0, pk = 0;
        if (e < E) {
            int s = src[e];
            int d = dst[e];
            int b = d >> 8;                     // NPB = 256
            int r = atomicAdd(&lcnt[b], 1);     // r < 4096
            pk = (r << 8) | b;
            pv = (s << 8) | (d & 255);
        }
        pp[i] = pv; rb[i] = pk;
    }
    __syncthreads();
    lbase[tid] = lcnt[tid] ? atomicAdd(&bcursor[tid], lcnt[tid]) : 0;
    __syncthreads();
#pragma unroll
    for (int i = 0; i < 16; ++i) {
        int e = base + i * 256 + tid;
        if (e < E) {
            int b = rb[i] & 255;
            int r = rb[i] >> 8;
            part[(size_t)(lbase[b] + r)] = pp[i];
        }
    }
}

// ---- per-bucket counting sort with LDS-staged edge slice ----
// One 512-thread block per bucket (196 blocks -> 1/CU). Bucket slice (~33KB)
// staged in LDS once; count + scan + scatter all read LDS. Overflow (>BSBUF,
// ~never: mean 8192, sigma 90) falls back to global reads. Zero global atomics.
__global__ __launch_bounds__(512) void k_bucket_sort(const int* __restrict__ part,
                                                     const int* __restrict__ bbase,
                                                     int* __restrict__ row_ptr,
                                                     float* __restrict__ dinv,
                                                     int* __restrict__ csr_src,
                                                     int N, int E) {
    __shared__ int lcnt[256];
    __shared__ int lcur[256];
    __shared__ int sbuf[256];
    __shared__ int ebuf[BSBUF];
    int tid = threadIdx.x;
    int b = blockIdx.x;
    int beg = bbase[b], end = bbase[b + 1];
    int cnt = end - beg;
    int lim = cnt < BSBUF ? cnt : BSBUF;
    for (int k = tid; k < lim; k += 512)
        ebuf[k] = part[beg + k];
    if (tid < 256) lcnt[tid] = 0;
    __syncthreads();
    for (int k = tid; k < lim; k += 512)
        atomicAdd(&lcnt[ebuf[k] & (NPB - 1)], 1);
    for (int k = BSBUF + tid; k < cnt; k += 512)
        atomicAdd(&lcnt[part[beg + k] & (NPB - 1)], 1);
    __syncthreads();
    int v = (tid < 256) ? lcnt[tid] : 0;
    if (tid < 256) sbuf[tid] = v;
    __syncthreads();
    for (int off = 1; off < 256; off <<= 1) {
        int t = (tid >= off && tid < 256) ? sbuf[tid - off] : 0;
        __syncthreads();
        if (tid < 256) sbuf[tid] += t;
        __syncthreads();
    }
    if (tid < 256) {
        int loff = sbuf[tid] - v;        // exclusive within-bucket offset
        lcur[tid] = beg + loff;
        int node = b * NPB + tid;
        if (node < N) {
            row_ptr[node] = beg + loff;
            dinv[node] = rsqrtf((float)(v + 1));   // +1 self loop
        }
        if (node == 0) row_ptr[N] = E;
    }
    __syncthreads();
    for (int k = tid; k < lim; k += 512) {
        int p = ebuf[k];
        int pos = atomicAdd(&lcur[p & (NPB - 1)], 1);
        csr_src[pos] = p >> 8;
    }
    for (int k = BSBUF + tid; k < cnt; k += 512) {
        int p = part[beg + k];
        int pos = atomicAdd(&lcur[p & (NPB - 1)], 1);
        csr_src[pos] = p >> 8;
    }
}

// ---------------- MFMA GEMM: Cb(MxHID, bf16) = (A(MxK, fp32) @ W) * dinv[row] ----------------
// R6 measured-best shape: LDS-free (A has zero cross-thread reuse), 16 rows/wave,
// direct per-lane f32x4 global loads (four quads cover a contiguous 128B window
// per row). No barrier, no LDS; occupancy limited only by VGPRs.
template<int K>
__global__ __launch_bounds__(128) void k_gemm_mfma(const float* __restrict__ A,
                                                   const short* __restrict__ Bf,
                                                   const float* __restrict__ dinv,
                                                   unsigned short* __restrict__ Cb, int M) {
    constexpr int KC = K / 32;
    int tid = threadIdx.x;
    int base = blockIdx.x * 32;
    int lane = tid & 63;
    int w = tid >> 6;
    int quad = lane >> 4;
    int mrow = base + w * 16 + (lane & 15);
    bool valid = (mrow < M);
    const float* arow = A + (size_t)mrow * K;
    f32x4 acc[8] = {};
    const bf16x8* BfH = (const bf16x8*)Bf;
    const bf16x8* BfL = (const bf16x8*)(Bf + (size_t)K * HID);

#pragma unroll 2
    for (int kc = 0; kc < KC; ++kc) {
        f32x4 a0 = {0.f, 0.f, 0.f, 0.f};
        f32x4 a1 = {0.f, 0.f, 0.f, 0.f};
        if (valid) {
            a0 = *(const f32x4*)(arow + kc * 32 + quad * 8);
            a1 = *(const f32x4*)(arow + kc * 32 + quad * 8 + 4);
        }
        bf16x8 ahi, alo;
#pragma unroll
        for (int j2 = 0; j2 < 4; ++j2) {
            short hi, lo;
            split_bf16(a0[j2], hi, lo);
            ahi[j2] = hi; alo[j2] = lo;
            split_bf16(a1[j2], hi, lo);
            ahi[4 + j2] = hi; alo[4 + j2] = lo;
        }
        bf16x8 bh[8], bl[8];
        size_t boff = ((size_t)kc * 8) * 64 + lane;
#pragma unroll
        for (int nt = 0; nt < 8; ++nt) {
            bh[nt] = BfH[boff + (size_t)nt * 64];
            bl[nt] = BfL[boff + (size_t)nt * 64];
        }
#pragma unroll
        for (int nt = 0; nt < 8; ++nt)
            acc[nt] = __builtin_amdgcn_mfma_f32_16x16x32_bf16(ahi, bh[nt], acc[nt], 0, 0, 0);
#pragma unroll
        for (int nt = 0; nt < 8; ++nt)
            acc[nt] = __builtin_amdgcn_mfma_f32_16x16x32_bf16(alo, bh[nt], acc[nt], 0, 0, 0);
#pragma unroll
        for (int nt = 0; nt < 8; ++nt)
            acc[nt] = __builtin_amdgcn_mfma_f32_16x16x32_bf16(ahi, bl[nt], acc[nt], 0, 0, 0);
    }

    // epilogue: scale row by dinv[m], quantize to bf16 (RNE)
    int mbase = base + w * 16 + quad * 4;
    int ncol = lane & 15;
    float dsc[4];
#pragma unroll
    for (int r = 0; r < 4; ++r)
        dsc[r] = (mbase + r < M) ? dinv[mbase + r] : 0.f;
#pragma unroll
    for (int nt = 0; nt < 8; ++nt) {
#pragma unroll
        for (int r = 0; r < 4; ++r) {
            int m = mbase + r;
            if (m < M) {
                __hip_bfloat16 b = __float2bfloat16(acc[nt][r] * dsc[r]);
                Cb[(size_t)m * HID + nt * 16 + ncol] = __builtin_bit_cast(unsigned short, b);
            }
        }
    }
}

// ---------------- CSR aggregation over bf16 gather buffer ----------------
// Wave-per-node: lane = e4*16 + t; e4 in [0,4) processes every 4th edge,
// t in [0,16) owns features [t*8, t*8+8) via one 16B bf16x8 load per edge.
// out[n] = dinv[n] * (hs[n] + sum_in hs[src]) + bias  (+relu), fp32 accumulate/out
__global__ __launch_bounds__(256) void k_agg(const unsigned short* __restrict__ hs,
                                             const int* __restrict__ row_ptr,
                                             const int* __restrict__ csr_src,
                                             const float* __restrict__ dinv,
                                             const float* __restrict__ bias,
                                             float* __restrict__ out, int relu, int M) {
    int n = blockIdx.x * 4 + (threadIdx.x >> 6);   // one wave per node
    if (n >= M) return;
    int lane = threadIdx.x & 63;
    int e4 = lane >> 4;       // edge sub-group 0..3
    int t  = lane & 15;       // feature group: 8 bf16 = 16B per lane

    int beg = row_ptr[n];
    int end = row_ptr[n + 1];

    float acc[8] = {0.f, 0.f, 0.f, 0.f, 0.f, 0.f, 0.f, 0.f};
    if (e4 == 0) {
        // self loop (hs pre-scaled by dinv[src])
        bf16x8 v = *(const bf16x8*)(hs + (size_t)n * HID + t * 8);
#pragma unroll
        for (int j = 0; j < 8; ++j) acc[j] = bf2f((unsigned short)v[j]);
    }

    int k = beg + e4;
    for (; k + 12 < end; k += 16) {
        int s0 = csr_src[k];
        int s1 = csr_src[k + 4];
        int s2 = csr_src[k + 8];
        int s3 = csr_src[k + 12];
        bf16x8 v0 = *(const bf16x8*)(hs + (size_t)s0 * HID + t * 8);
        bf16x8 v1 = *(const bf16x8*)(hs + (size_t)s1 * HID + t * 8);
        bf16x8 v2 = *(const bf16x8*)(hs + (size_t)s2 * HID + t * 8);
        bf16x8 v3 = *(const bf16x8*)(hs + (size_t)s3 * HID + t * 8);
#pragma unroll
        for (int j = 0; j < 8; ++j)
            acc[j] += (bf2f((unsigned short)v0[j]) + bf2f((unsigned short)v1[j]))
                    + (bf2f((unsigned short)v2[j]) + bf2f((unsigned short)v3[j]));
    }
    for (; k + 4 < end; k += 8) {
        int s0 = csr_src[k];
        int s1 = csr_src[k + 4];
        bf16x8 v0 = *(const bf16x8*)(hs + (size_t)s0 * HID + t * 8);
        bf16x8 v1 = *(const bf16x8*)(hs + (size_t)s1 * HID + t * 8);
#pragma unroll
        for (int j = 0; j < 8; ++j)
            acc[j] += bf2f((unsigned short)v0[j]) + bf2f((unsigned short)v1[j]);
    }
    if (k < end) {
        int s0 = csr_src[k];
        bf16x8 v0 = *(const bf16x8*)(hs + (size_t)s0 * HID + t * 8);
#pragma unroll
        for (int j = 0; j < 8; ++j)
            acc[j] += bf2f((unsigned short)v0[j]);
    }

    // reduce the 4 e4-groups (lanes differing in bits 4,5)
#pragma unroll
    for (int j = 0; j < 8; ++j) acc[j] += __shfl_xor(acc[j], 16, 64);
#pragma unroll
    for (int j = 0; j < 8; ++j) acc[j] += __shfl_xor(acc[j], 32, 64);

    if (e4 == 0) {
        float d = dinv[n];
        f32x4 o0, o1;
#pragma unroll
        for (int j = 0; j < 4; ++j) {
            float a = acc[j] * d + bias[t * 8 + j];
            if (relu) a = fmaxf(a, 0.f);
            o0[j] = a;
        }
#pragma unroll
        for (int j = 0; j < 4; ++j) {
            float a = acc[4 + j] * d + bias[t * 8 + 4 + j];
            if (relu) a = fmaxf(a, 0.f);
            o1[j] = a;
        }
        *(f32x4*)(out + (size_t)n * HID + t * 8)     = o0;
        *(f32x4*)(out + (size_t)n * HID + t * 8 + 4) = o1;
    }
}

// ---------------- final linear: out = pooled @ Wl + bl (MFMA, split-K) ----------------
__global__ void k_final_init(const float* __restrict__ bl, float* __restrict__ out, int total) {
    int t = blockIdx.x * blockDim.x + threadIdx.x;
    if (t < total) out[t] = bl[t & (HID - 1)];
}

// 256 threads (4 waves), BM=128 M-rows per block (wave w owns rows w*32..w*32+31
// as 2 MFMA m-fragments), K-slice KS per blockIdx.y, LDS tile TILE cols at a time.
// B traffic = nx * 3.27MB = 26MB regardless of split-K depth. KS=256 -> 25
// K-slices -> 200 blocks / 800 waves for latency hiding.
template<int KS, int TILE>
__global__ __launch_bounds__(256) void k_final_mfma(const float* __restrict__ emb,
                                                    const short* __restrict__ Bf,
                                                    float* __restrict__ out, int M) {
    constexpr int BM = 128;
    constexpr int LDA = TILE + 4;
    __shared__ float As[BM * LDA];
    int tid = threadIdx.x;
    int g0 = blockIdx.x * BM;
    int k0 = blockIdx.y * KS;
    int lane = tid & 63;
    int w = tid >> 6;
    int quad = lane >> 4;
    f32x4 acc[2][8] = {};
    const bf16x8* BfH = (const bf16x8*)Bf;
    const bf16x8* BfL = (const bf16x8*)(Bf + (size_t)KFIN * HID);

    for (int t = 0; t < KS / TILE; ++t) {
        __syncthreads();
        constexpr int ITERS = (BM * (TILE / 4)) / 256;
#pragma unroll
        for (int i = 0; i < ITERS; ++i) {
            int f4 = tid + i * 256;
            int row = f4 / (TILE / 4);
            int c4 = f4 % (TILE / 4);
            f32x4 v = {0.f, 0.f, 0.f, 0.f};
            int m = g0 + row;
            if (m < M) v = *(const f32x4*)(emb + (size_t)m * KFIN + k0 + t * TILE + c4 * 4);
            *(f32x4*)(&As[row * LDA + c4 * 4]) = v;
        }
        __syncthreads();
        for (int kc = 0; kc < TILE / 32; ++kc) {
            int kcg = (k0 + t * TILE) / 32 + kc;
            bf16x8 bh[8], bl[8];
            size_t boff = (size_t)kcg * 8 * 64 + lane;
#pragma unroll
            for (int nt = 0; nt < 8; ++nt) {
                bh[nt] = BfH[boff + (size_t)nt * 64];
                bl[nt] = BfL[boff + (size_t)nt * 64];
            }
#pragma unroll
            for (int f = 0; f < 2; ++f) {
                int mrow = w * 32 + f * 16 + (lane & 15);
                const float* ap = &As[mrow * LDA + kc * 32 + quad * 8];
                f32x4 a0 = *(const f32x4*)ap;
                f32x4 a1 = *(const f32x4*)(ap + 4);
                bf16x8 ahi, alo;
#pragma unroll
                for (int j2 = 0; j2 < 4; ++j2) {
                    short hi, lo;
                    split_bf16(a0[j2], hi, lo);
                    ahi[j2] = hi; alo[j2] = lo;
                    split_bf16(a1[j2], hi, lo);
                    ahi[4 + j2] = hi; alo[4 + j2] = lo;
                }
#pragma unroll
                for (int nt = 0; nt < 8; ++nt) {
                    acc[f][nt] = __builtin_amdgcn_mfma_f32_16x16x32_bf16(ahi, bh[nt], acc[f][nt], 0, 0, 0);
                    acc[f][nt] = __builtin_amdgcn_mfma_f32_16x16x32_bf16(alo, bh[nt], acc[f][nt], 0, 0, 0);
                    acc[f][nt] = __builtin_amdgcn_mfma_f32_16x16x32_bf16(ahi, bl[nt], acc[f][nt], 0, 0, 0);
                }
            }
        }
    }

    int ncol = lane & 15;
#pragma unroll
    for (int f = 0; f < 2; ++f) {
        int mbase = g0 + w * 32 + f * 16 + quad * 4;
#pragma unroll
        for (int nt = 0; nt < 8; ++nt) {
#pragma unroll
            for (int r = 0; r < 4; ++r) {
                int m = mbase + r;
                if (m < M) atomicAdd(&out[(size_t)m * HID + nt * 16 + ncol], acc[f][nt][r]);
            }
        }
    }
}

extern "C" void kernel_launch(void* const* d_in, const int* in_sizes, int n_in,
                              void* d_out, int out_size, void* d_ws, size_t ws_size,
                              hipStream_t stream) {
    const float* x  = (const float*)d_in[0];
    const float* W1 = (const float*)d_in[1];
    const float* b1 = (const float*)d_in[2];
    const float* W2 = (const float*)d_in[3];
    const float* b2 = (const float*)d_in[4];
    const float* Wl = (const float*)d_in[5];
    const float* bl = (const float*)d_in[6];
    const int* edge = (const int*)d_in[7];

    const int N = in_sizes[0] / F_IN;       // 50000
    const int E = in_sizes[7] / 2;          // 1600000
    const int G = N / SSUB;                 // 1000
    const int NH = N * HID;
    const int nbkt = (N + NPB - 1) / NPB;   // 196 coarse buckets

    const int* src = edge;
    const int* dst = edge + E;

    // workspace layout
    char* ws = (char*)d_ws;
    float* dinv    = (float*)ws;                 ws += (size_t)N * 4;
    int*   row_ptr = (int*)ws;                   ws += (size_t)(N + 64) * 4;
    int*   bcnt    = (int*)ws;                   ws += (size_t)256 * 4;
    int*   bbase   = (int*)ws;                   ws += (size_t)320 * 4;
    int*   bcursor = (int*)ws;                   ws += (size_t)256 * 4;
    int*   csr_src = (int*)ws;                   ws += (size_t)E * 4;
    int*   part    = (int*)ws;                   ws += (size_t)E * 4;   // packed (src<<8|dst&255)
    unsigned short* hs0 = (unsigned short*)ws;   ws += (size_t)NH * 2;  // bf16 gather buf L1
    unsigned short* hs1 = (unsigned short*)ws;   ws += (size_t)NH * 2;  // bf16 gather buf L2
    float* h       = (float*)ws;                 ws += (size_t)NH * 4;  // fp32 relu'd hidden
    short* Bf1     = (short*)ws;                 ws += (size_t)2 * F_IN * HID * 2;  // hi+lo bf16
    short* Bf2     = (short*)ws;                 ws += (size_t)2 * HID * HID * 2;
    short* Bfl     = (short*)ws;                 ws += (size_t)2 * KFIN * HID * 2;

    float* out_final = (float*)d_out;                 // G*H
    float* emb       = out_final + (size_t)G * HID;   // N*H

    // ---- fused prep (wsplit x3 + bucket histogram) ----
    hipMemsetAsync(bcnt, 0, 256 * sizeof(int), stream);
    {
        const int nb1 = (F_IN * HID + 255) / 256;   // 128
        const int nb2 = (HID * HID + 255) / 256;    // 64
        const int nbl = (KFIN * HID + 255) / 256;   // 3200
        const int nbh = ((E >> 2) + 255) / 256;     // 1563
        k_prep<<<nb1 + nb2 + nbl + nbh, 256, 0, stream>>>(W1, Bf1, W2, Bf2, Wl, Bfl,
                                                          dst, bcnt, E, nb1, nb2, nbl, nbh);
    }
    k_bscan<<<1, 256, 0, stream>>>(bcnt, bbase, bcursor);
    k_partition<<<(E + 4095) / 4096, 256, 0, stream>>>(src, dst, bcursor, part, E);
    k_bucket_sort<<<nbkt, 512, 0, stream>>>(part, bbase, row_ptr, dinv, csr_src, N, E);

    // ---- layer 1 ----
    k_gemm_mfma<F_IN><<<(N + 31) / 32, 128, 0, stream>>>(x, Bf1, dinv, hs0, N);  // hs0 = bf16((x@W1)*dinv)
    k_agg<<<(N + 3) / 4, 256, 0, stream>>>(hs0, row_ptr, csr_src, dinv, b1, h, 1, N);

    // ---- layer 2 ----
    k_gemm_mfma<HID><<<(N + 31) / 32, 128, 0, stream>>>(h, Bf2, dinv, hs1, N);   // hs1 = bf16((h@W2)*dinv)
    k_agg<<<(N + 3) / 4, 256, 0, stream>>>(hs1, row_ptr, csr_src, dinv, b2, emb, 0, N);

    // ---- final linear (bias init + MFMA split-K accumulate, BM=128, 25 K-slices) ----
    k_final_init<<<(G * HID + 255) / 256, 256, 0, stream>>>(bl, out_final, G * HID);
    {
        dim3 grid((G + 127) / 128, KFIN / 256);   // (8, 25) = 200 blocks
        k_final_mfma<256, 32><<<grid, 256, 0, stream>>>(emb, Bfl, out_final, G);
    }
}

// Round 10
// 356.467 us; speedup vs baseline: 1.0362x; 1.0021x over previous
//
#include <hip/hip_runtime.h>
#include <hip/hip_bf16.h>

#define F_IN 256
#define HID  128
#define SSUB 50
#define KFIN 6400   // SSUB * HID
#define NPB  256    // nodes per partition bucket (power of 2: bucket = dst >> 8)
#define BSBUF 10240 // LDS edge-buffer ints for bucket_sort (mean bucket 8192, +22σ)

typedef __attribute__((ext_vector_type(4))) float f32x4;
typedef __attribute__((ext_vector_type(8))) short bf16x8;

__device__ __forceinline__ void split_bf16(float v, short& hi, short& lo) {
    __hip_bfloat16 h = __float2bfloat16(v);
    float hf = __bfloat162float(h);
    __hip_bfloat16 l = __float2bfloat16(v - hf);   // exact residual, then RNE to bf16
    hi = __builtin_bit_cast(short, h);
    lo = __builtin_bit_cast(short, l);
}

__device__ __forceinline__ float bf2f(unsigned short u) {
    return __builtin_bit_cast(float, (unsigned)u << 16);
}

// ---------------- fused prep: wsplit(W1)+wsplit(W2)+wsplit(Wl)+bhist ----------------
// All four are mutually independent; fusing packs complementary profiles
// (bhist = atomic/latency-bound, wsplit = VALU/write-bound) into one dispatch.

// One thread per FRAGMENT (8 bf16 = 16B): reads 8 W elements (16 consecutive
// lanes cover 64B contiguous per j), stores hi/lo as single 16B coalesced
// vector stores (wave = 1KB/store). Replaces the per-element version whose
// 2B stride-16B scattered stores caused ~8x write-line amplification.
template<int K>
__device__ __forceinline__ void wsplit_body(const float* __restrict__ W,
                                            short* __restrict__ Bf, int blk) {
    constexpr int NF = (K / 32) * 8 * 64;   // fragments
    int f = blk * 256 + threadIdx.x;
    if (f >= NF) return;
    int lane = f & 63;
    int nt = (f >> 6) & 7;
    int kc = f >> 9;
    int quad = lane >> 4, nc = lane & 15;
    int n = nt * 16 + nc;
    int k0 = kc * 32 + quad * 8;
    bf16x8 hi8, lo8;
#pragma unroll
    for (int j = 0; j < 8; ++j) {
        short hi, lo;
        split_bf16(W[(size_t)(k0 + j) * HID + n], hi, lo);
        hi8[j] = hi; lo8[j] = lo;
    }
    ((bf16x8*)Bf)[f] = hi8;
    ((bf16x8*)(Bf + (size_t)K * HID))[f] = lo8;
}

__device__ __forceinline__ void bhist_body(const int* __restrict__ dst,
                                           int* __restrict__ bcnt,
                                           int E, int blk, int nbh) {
    __shared__ int lcnt[256];
    int tid = threadIdx.x;
    lcnt[tid] = 0;
    __syncthreads();
    int n4 = E >> 2;
    int stride = nbh * 256;
    for (int i = blk * 256 + tid; i < n4; i += stride) {
        int4 d = ((const int4*)dst)[i];
        atomicAdd(&lcnt[d.x >> 8], 1);
        atomicAdd(&lcnt[d.y >> 8], 1);
        atomicAdd(&lcnt[d.z >> 8], 1);
        atomicAdd(&lcnt[d.w >> 8], 1);
    }
    if (blk == 0) {
        for (int e = (n4 << 2) + tid; e < E; e += 256)
            atomicAdd(&lcnt[dst[e] >> 8], 1);
    }
    __syncthreads();
    if (lcnt[tid]) atomicAdd(&bcnt[tid], lcnt[tid]);
}

__global__ __launch_bounds__(256) void k_prep(const float* __restrict__ W1, short* __restrict__ Bf1,
                                              const float* __restrict__ W2, short* __restrict__ Bf2,
                                              const float* __restrict__ Wl, short* __restrict__ Bfl,
                                              const int* __restrict__ dst, int* __restrict__ bcnt,
                                              int E, int nb1, int nb2, int nbl, int nbh) {
    int b = blockIdx.x;
    if (b < nb1) { wsplit_body<F_IN>(W1, Bf1, b); return; }
    b -= nb1;
    if (b < nb2) { wsplit_body<HID>(W2, Bf2, b); return; }
    b -= nb2;
    if (b < nbl) { wsplit_body<KFIN>(Wl, Bfl, b); return; }
    b -= nbl;
    bhist_body(dst, bcnt, E, b, nbh);
}

// exclusive scan of 256 bucket counts -> bbase[0..256]; bcursor = copy for partition
__global__ void k_bscan(const int* __restrict__ bcnt, int* __restrict__ bbase,
                        int* __restrict__ bcursor) {
    __shared__ int buf[256];
    int tid = threadIdx.x;
    int v = bcnt[tid];
    buf[tid] = v;
    __syncthreads();
    for (int off = 1; off < 256; off <<= 1) {
        int t = (tid >= off) ? buf[tid - off] : 0;
        __syncthreads();
        buf[tid] += t;
        __syncthreads();
    }
    int ex = buf[tid] - v;
    bbase[tid] = ex;
    bcursor[tid] = ex;
    if (tid == 255) bbase[256] = buf[255];
}

// ---- partition edges into coarse buckets (dst>>8), block-batched append ----
// 4096 edges per block; LDS count -> one global reservation per bucket per block ->
// append packed (src<<8 | dst&255) ints (src < 2^24). 4B/edge instead of 8B.
__global__ __launch_bounds__(256) void k_partition(const int* __restrict__ src,
                                                   const int* __restrict__ dst,
                                                   int* __restrict__ bcursor,
                                                   int* __restrict__ part, int E) {
    __shared__ int lcnt[256];
    __shared__ int lbase[256];
    int tid = threadIdx.x;
    lcnt[tid] = 0;
    __syncthreads();
    int base = blockIdx.x * 4096;
    int pp[16], rb[16];
#pragma unroll
    for (int i = 0; i < 16; ++i) {
        int e = base + i * 256 + tid;
        int pv = 0, pk = 0;
        if (e < E) {
            int s = src[e];
            int d = dst[e];
            int b = d >> 8;                     // NPB = 256
            int r = atomicAdd(&lcnt[b], 1);     // r < 4096
            pk = (r << 8) | b;
            pv = (s << 8) | (d & 255);
        }
        pp[i] = pv; rb[i] = pk;
    }
    __syncthreads();
    lbase[tid] = lcnt[tid] ? atomicAdd(&bcursor[tid], lcnt[tid]) : 0;
    __syncthreads();
#pragma unroll
    for (int i = 0; i < 16; ++i) {
        int e = base + i * 256 + tid;
        if (e < E) {
            int b = rb[i] & 255;
            int r = rb[i] >> 8;
            part[(size_t)(lbase[b] + r)] = pp[i];
        }
    }
}

// ---- per-bucket counting sort with LDS-staged edge slice ----
// One 512-thread block per bucket (196 blocks -> 1/CU). Bucket slice (~33KB)
// staged in LDS once; count + scan + scatter all read LDS. Overflow (>BSBUF,
// ~never: mean 8192, sigma 90) falls back to global reads. Zero global atomics.
__global__ __launch_bounds__(512) void k_bucket_sort(const int* __restrict__ part,
                                                     const int* __restrict__ bbase,
                                                     int* __restrict__ row_ptr,
                                                     float* __restrict__ dinv,
                                                     int* __restrict__ csr_src,
                                                     int N, int E) {
    __shared__ int lcnt[256];
    __shared__ int lcur[256];
    __shared__ int sbuf[256];
    __shared__ int ebuf[BSBUF];
    int tid = threadIdx.x;
    int b = blockIdx.x;
    int beg = bbase[b], end = bbase[b + 1];
    int cnt = end - beg;
    int lim = cnt < BSBUF ? cnt : BSBUF;
    for (int k = tid; k < lim; k += 512)
        ebuf[k] = part[beg + k];
    if (tid < 256) lcnt[tid] = 0;
    __syncthreads();
    for (int k = tid; k < lim; k += 512)
        atomicAdd(&lcnt[ebuf[k] & (NPB - 1)], 1);
    for (int k = BSBUF + tid; k < cnt; k += 512)
        atomicAdd(&lcnt[part[beg + k] & (NPB - 1)], 1);
    __syncthreads();
    int v = (tid < 256) ? lcnt[tid] : 0;
    if (tid < 256) sbuf[tid] = v;
    __syncthreads();
    for (int off = 1; off < 256; off <<= 1) {
        int t = (tid >= off && tid < 256) ? sbuf[tid - off] : 0;
        __syncthreads();
        if (tid < 256) sbuf[tid] += t;
        __syncthreads();
    }
    if (tid < 256) {
        int loff = sbuf[tid] - v;        // exclusive within-bucket offset
        lcur[tid] = beg + loff;
        int node = b * NPB + tid;
        if (node < N) {
            row_ptr[node] = beg + loff;
            dinv[node] = rsqrtf((float)(v + 1));   // +1 self loop
        }
        if (node == 0) row_ptr[N] = E;
    }
    __syncthreads();
    for (int k = tid; k < lim; k += 512) {
        int p = ebuf[k];
        int pos = atomicAdd(&lcur[p & (NPB - 1)], 1);
        csr_src[pos] = p >> 8;
    }
    for (int k = BSBUF + tid; k < cnt; k += 512) {
        int p = part[beg + k];
        int pos = atomicAdd(&lcur[p & (NPB - 1)], 1);
        csr_src[pos] = p >> 8;
    }
}

// ---------------- MFMA GEMM: Cb(MxHID, bf16) = (A(MxK, fp32) @ W) * dinv[row] ----------------
// R6 measured-best shape: LDS-free (A has zero cross-thread reuse), 16 rows/wave,
// direct per-lane f32x4 global loads (four quads cover a contiguous 128B window
// per row). No barrier, no LDS; occupancy limited only by VGPRs.
template<int K>
__global__ __launch_bounds__(128) void k_gemm_mfma(const float* __restrict__ A,
                                                   const short* __restrict__ Bf,
                                                   const float* __restrict__ dinv,
                                                   unsigned short* __restrict__ Cb, int M) {
    constexpr int KC = K / 32;
    int tid = threadIdx.x;
    int base = blockIdx.x * 32;
    int lane = tid & 63;
    int w = tid >> 6;
    int quad = lane >> 4;
    int mrow = base + w * 16 + (lane & 15);
    bool valid = (mrow < M);
    const float* arow = A + (size_t)mrow * K;
    f32x4 acc[8] = {};
    const bf16x8* BfH = (const bf16x8*)Bf;
    const bf16x8* BfL = (const bf16x8*)(Bf + (size_t)K * HID);

#pragma unroll 2
    for (int kc = 0; kc < KC; ++kc) {
        f32x4 a0 = {0.f, 0.f, 0.f, 0.f};
        f32x4 a1 = {0.f, 0.f, 0.f, 0.f};
        if (valid) {
            a0 = *(const f32x4*)(arow + kc * 32 + quad * 8);
            a1 = *(const f32x4*)(arow + kc * 32 + quad * 8 + 4);
        }
        bf16x8 ahi, alo;
#pragma unroll
        for (int j2 = 0; j2 < 4; ++j2) {
            short hi, lo;
            split_bf16(a0[j2], hi, lo);
            ahi[j2] = hi; alo[j2] = lo;
            split_bf16(a1[j2], hi, lo);
            ahi[4 + j2] = hi; alo[4 + j2] = lo;
        }
        bf16x8 bh[8], bl[8];
        size_t boff = ((size_t)kc * 8) * 64 + lane;
#pragma unroll
        for (int nt = 0; nt < 8; ++nt) {
            bh[nt] = BfH[boff + (size_t)nt * 64];
            bl[nt] = BfL[boff + (size_t)nt * 64];
        }
#pragma unroll
        for (int nt = 0; nt < 8; ++nt)
            acc[nt] = __builtin_amdgcn_mfma_f32_16x16x32_bf16(ahi, bh[nt], acc[nt], 0, 0, 0);
#pragma unroll
        for (int nt = 0; nt < 8; ++nt)
            acc[nt] = __builtin_amdgcn_mfma_f32_16x16x32_bf16(alo, bh[nt], acc[nt], 0, 0, 0);
#pragma unroll
        for (int nt = 0; nt < 8; ++nt)
            acc[nt] = __builtin_amdgcn_mfma_f32_16x16x32_bf16(ahi, bl[nt], acc[nt], 0, 0, 0);
    }

    // epilogue: scale row by dinv[m], quantize to bf16 (RNE)
    int mbase = base + w * 16 + quad * 4;
    int ncol = lane & 15;
    float dsc[4];
#pragma unroll
    for (int r = 0; r < 4; ++r)
        dsc[r] = (mbase + r < M) ? dinv[mbase + r] : 0.f;
#pragma unroll
    for (int nt = 0; nt < 8; ++nt) {
#pragma unroll
        for (int r = 0; r < 4; ++r) {
            int m = mbase + r;
            if (m < M) {
                __hip_bfloat16 b = __float2bfloat16(acc[nt][r] * dsc[r]);
                Cb[(size_t)m * HID + nt * 16 + ncol] = __builtin_bit_cast(unsigned short, b);
            }
        }
    }
}

// ---------------- CSR aggregation over bf16 gather buffer ----------------
// Wave-per-node: lane = e4*16 + t; e4 in [0,4) processes every 4th edge,
// t in [0,16) owns features [t*8, t*8+8) via one 16B bf16x8 load per edge.
// out[n] = dinv[n] * (hs[n] + sum_in hs[src]) + bias  (+relu), fp32 accumulate/out
__global__ __launch_bounds__(256) void k_agg(const unsigned short* __restrict__ hs,
                                             const int* __restrict__ row_ptr,
                                             const int* __restrict__ csr_src,
                                             const float* __restrict__ dinv,
                                             const float* __restrict__ bias,
                                             float* __restrict__ out, int relu, int M) {
    int n = blockIdx.x * 4 + (threadIdx.x >> 6);   // one wave per node
    if (n >= M) return;
    int lane = threadIdx.x & 63;
    int e4 = lane >> 4;       // edge sub-group 0..3
    int t  = lane & 15;       // feature group: 8 bf16 = 16B per lane

    int beg = row_ptr[n];
    int end = row_ptr[n + 1];

    float acc[8] = {0.f, 0.f, 0.f, 0.f, 0.f, 0.f, 0.f, 0.f};
    if (e4 == 0) {
        // self loop (hs pre-scaled by dinv[src])
        bf16x8 v = *(const bf16x8*)(hs + (size_t)n * HID + t * 8);
#pragma unroll
        for (int j = 0; j < 8; ++j) acc[j] = bf2f((unsigned short)v[j]);
    }

    int k = beg + e4;
    for (; k + 12 < end; k += 16) {
        int s0 = csr_src[k];
        int s1 = csr_src[k + 4];
        int s2 = csr_src[k + 8];
        int s3 = csr_src[k + 12];
        bf16x8 v0 = *(const bf16x8*)(hs + (size_t)s0 * HID + t * 8);
        bf16x8 v1 = *(const bf16x8*)(hs + (size_t)s1 * HID + t * 8);
        bf16x8 v2 = *(const bf16x8*)(hs + (size_t)s2 * HID + t * 8);
        bf16x8 v3 = *(const bf16x8*)(hs + (size_t)s3 * HID + t * 8);
#pragma unroll
        for (int j = 0; j < 8; ++j)
            acc[j] += (bf2f((unsigned short)v0[j]) + bf2f((unsigned short)v1[j]))
                    + (bf2f((unsigned short)v2[j]) + bf2f((unsigned short)v3[j]));
    }
    for (; k + 4 < end; k += 8) {
        int s0 = csr_src[k];
        int s1 = csr_src[k + 4];
        bf16x8 v0 = *(const bf16x8*)(hs + (size_t)s0 * HID + t * 8);
        bf16x8 v1 = *(const bf16x8*)(hs + (size_t)s1 * HID + t * 8);
#pragma unroll
        for (int j = 0; j < 8; ++j)
            acc[j] += bf2f((unsigned short)v0[j]) + bf2f((unsigned short)v1[j]);
    }
    if (k < end) {
        int s0 = csr_src[k];
        bf16x8 v0 = *(const bf16x8*)(hs + (size_t)s0 * HID + t * 8);
#pragma unroll
        for (int j = 0; j < 8; ++j)
            acc[j] += bf2f((unsigned short)v0[j]);
    }

    // reduce the 4 e4-groups (lanes differing in bits 4,5)
#pragma unroll
    for (int j = 0; j < 8; ++j) acc[j] += __shfl_xor(acc[j], 16, 64);
#pragma unroll
    for (int j = 0; j < 8; ++j) acc[j] += __shfl_xor(acc[j], 32, 64);

    if (e4 == 0) {
        float d = dinv[n];
        f32x4 o0, o1;
#pragma unroll
        for (int j = 0; j < 4; ++j) {
            float a = acc[j] * d + bias[t * 8 + j];
            if (relu) a = fmaxf(a, 0.f);
            o0[j] = a;
        }
#pragma unroll
        for (int j = 0; j < 4; ++j) {
            float a = acc[4 + j] * d + bias[t * 8 + 4 + j];
            if (relu) a = fmaxf(a, 0.f);
            o1[j] = a;
        }
        *(f32x4*)(out + (size_t)n * HID + t * 8)     = o0;
        *(f32x4*)(out + (size_t)n * HID + t * 8 + 4) = o1;
    }
}

// ---------------- final linear: out = pooled @ Wl + bl (MFMA, split-K) ----------------
__global__ void k_final_init(const float* __restrict__ bl, float* __restrict__ out, int total) {
    int t = blockIdx.x * blockDim.x + threadIdx.x;
    if (t < total) out[t] = bl[t & (HID - 1)];
}

// 256 threads (4 waves), BM=128 M-rows per block (wave w owns rows w*32..w*32+31
// as 2 MFMA m-fragments), K-slice KS per blockIdx.y, LDS tile TILE cols at a time.
// B traffic = nx * 3.27MB = 26MB regardless of split-K depth. KS=256 -> 25
// K-slices -> 200 blocks / 800 waves for latency hiding.
template<int KS, int TILE>
__global__ __launch_bounds__(256) void k_final_mfma(const float* __restrict__ emb,
                                                    const short* __restrict__ Bf,
                                                    float* __restrict__ out, int M) {
    constexpr int BM = 128;
    constexpr int LDA = TILE + 4;
    __shared__ float As[BM * LDA];
    int tid = threadIdx.x;
    int g0 = blockIdx.x * BM;
    int k0 = blockIdx.y * KS;
    int lane = tid & 63;
    int w = tid >> 6;
    int quad = lane >> 4;
    f32x4 acc[2][8] = {};
    const bf16x8* BfH = (const bf16x8*)Bf;
    const bf16x8* BfL = (const bf16x8*)(Bf + (size_t)KFIN * HID);

    for (int t = 0; t < KS / TILE; ++t) {
        __syncthreads();
        constexpr int ITERS = (BM * (TILE / 4)) / 256;
#pragma unroll
        for (int i = 0; i < ITERS; ++i) {
            int f4 = tid + i * 256;
            int row = f4 / (TILE / 4);
            int c4 = f4 % (TILE / 4);
            f32x4 v = {0.f, 0.f, 0.f, 0.f};
            int m = g0 + row;
            if (m < M) v = *(const f32x4*)(emb + (size_t)m * KFIN + k0 + t * TILE + c4 * 4);
            *(f32x4*)(&As[row * LDA + c4 * 4]) = v;
        }
        __syncthreads();
        for (int kc = 0; kc < TILE / 32; ++kc) {
            int kcg = (k0 + t * TILE) / 32 + kc;
            bf16x8 bh[8], bl[8];
            size_t boff = (size_t)kcg * 8 * 64 + lane;
#pragma unroll
            for (int nt = 0; nt < 8; ++nt) {
                bh[nt] = BfH[boff + (size_t)nt * 64];
                bl[nt] = BfL[boff + (size_t)nt * 64];
            }
#pragma unroll
            for (int f = 0; f < 2; ++f) {
                int mrow = w * 32 + f * 16 + (lane & 15);
                const float* ap = &As[mrow * LDA + kc * 32 + quad * 8];
                f32x4 a0 = *(const f32x4*)ap;
                f32x4 a1 = *(const f32x4*)(ap + 4);
                bf16x8 ahi, alo;
#pragma unroll
                for (int j2 = 0; j2 < 4; ++j2) {
                    short hi, lo;
                    split_bf16(a0[j2], hi, lo);
                    ahi[j2] = hi; alo[j2] = lo;
                    split_bf16(a1[j2], hi, lo);
                    ahi[4 + j2] = hi; alo[4 + j2] = lo;
                }
#pragma unroll
                for (int nt = 0; nt < 8; ++nt) {
                    acc[f][nt] = __builtin_amdgcn_mfma_f32_16x16x32_bf16(ahi, bh[nt], acc[f][nt], 0, 0, 0);
                    acc[f][nt] = __builtin_amdgcn_mfma_f32_16x16x32_bf16(alo, bh[nt], acc[f][nt], 0, 0, 0);
                    acc[f][nt] = __builtin_amdgcn_mfma_f32_16x16x32_bf16(ahi, bl[nt], acc[f][nt], 0, 0, 0);
                }
            }
        }
    }

    int ncol = lane & 15;
#pragma unroll
    for (int f = 0; f < 2; ++f) {
        int mbase = g0 + w * 32 + f * 16 + quad * 4;
#pragma unroll
        for (int nt = 0; nt < 8; ++nt) {
#pragma unroll
            for (int r = 0; r < 4; ++r) {
                int m = mbase + r;
                if (m < M) atomicAdd(&out[(size_t)m * HID + nt * 16 + ncol], acc[f][nt][r]);
            }
        }
    }
}

extern "C" void kernel_launch(void* const* d_in, const int* in_sizes, int n_in,
                              void* d_out, int out_size, void* d_ws, size_t ws_size,
                              hipStream_t stream) {
    const float* x  = (const float*)d_in[0];
    const float* W1 = (const float*)d_in[1];
    const float* b1 = (const float*)d_in[2];
    const float* W2 = (const float*)d_in[3];
    const float* b2 = (const float*)d_in[4];
    const float* Wl = (const float*)d_in[5];
    const float* bl = (const float*)d_in[6];
    const int* edge = (const int*)d_in[7];

    const int N = in_sizes[0] / F_IN;       // 50000
    const int E = in_sizes[7] / 2;          // 1600000
    const int G = N / SSUB;                 // 1000
    const int NH = N * HID;
    const int nbkt = (N + NPB - 1) / NPB;   // 196 coarse buckets

    const int* src = edge;
    const int* dst = edge + E;

    // workspace layout
    char* ws = (char*)d_ws;
    float* dinv    = (float*)ws;                 ws += (size_t)N * 4;
    int*   row_ptr = (int*)ws;                   ws += (size_t)(N + 64) * 4;
    int*   bcnt    = (int*)ws;                   ws += (size_t)256 * 4;
    int*   bbase   = (int*)ws;                   ws += (size_t)320 * 4;
    int*   bcursor = (int*)ws;                   ws += (size_t)256 * 4;
    int*   csr_src = (int*)ws;                   ws += (size_t)E * 4;
    int*   part    = (int*)ws;                   ws += (size_t)E * 4;   // packed (src<<8|dst&255)
    unsigned short* hs0 = (unsigned short*)ws;   ws += (size_t)NH * 2;  // bf16 gather buf L1
    unsigned short* hs1 = (unsigned short*)ws;   ws += (size_t)NH * 2;  // bf16 gather buf L2
    float* h       = (float*)ws;                 ws += (size_t)NH * 4;  // fp32 relu'd hidden
    short* Bf1     = (short*)ws;                 ws += (size_t)2 * F_IN * HID * 2;  // hi+lo bf16
    short* Bf2     = (short*)ws;                 ws += (size_t)2 * HID * HID * 2;
    short* Bfl     = (short*)ws;                 ws += (size_t)2 * KFIN * HID * 2;

    float* out_final = (float*)d_out;                 // G*H
    float* emb       = out_final + (size_t)G * HID;   // N*H

    // ---- fused prep (wsplit x3, fragment-per-thread + bucket histogram) ----
    hipMemsetAsync(bcnt, 0, 256 * sizeof(int), stream);
    {
        const int nb1 = ((F_IN / 32) * 8 * 64 + 255) / 256;   // 16
        const int nb2 = ((HID  / 32) * 8 * 64 + 255) / 256;   // 8
        const int nbl = ((KFIN / 32) * 8 * 64 + 255) / 256;   // 400
        const int nbh = ((E >> 2) + 255) / 256;               // 1563
        k_prep<<<nb1 + nb2 + nbl + nbh, 256, 0, stream>>>(W1, Bf1, W2, Bf2, Wl, Bfl,
                                                          dst, bcnt, E, nb1, nb2, nbl, nbh);
    }
    k_bscan<<<1, 256, 0, stream>>>(bcnt, bbase, bcursor);
    k_partition<<<(E + 4095) / 4096, 256, 0, stream>>>(src, dst, bcursor, part, E);
    k_bucket_sort<<<nbkt, 512, 0, stream>>>(part, bbase, row_ptr, dinv, csr_src, N, E);

    // ---- layer 1 ----
    k_gemm_mfma<F_IN><<<(N + 31) / 32, 128, 0, stream>>>(x, Bf1, dinv, hs0, N);  // hs0 = bf16((x@W1)*dinv)
    k_agg<<<(N + 3) / 4, 256, 0, stream>>>(hs0, row_ptr, csr_src, dinv, b1, h, 1, N);

    // ---- layer 2 ----
    k_gemm_mfma<HID><<<(N + 31) / 32, 128, 0, stream>>>(h, Bf2, dinv, hs1, N);   // hs1 = bf16((h@W2)*dinv)
    k_agg<<<(N + 3) / 4, 256, 0, stream>>>(hs1, row_ptr, csr_src, dinv, b2, emb, 0, N);

    // ---- final linear (bias init + MFMA split-K accumulate, BM=128, 25 K-slices) ----
    k_final_init<<<(G * HID + 255) / 256, 256, 0, stream>>>(bl, out_final, G * HID);
    {
        dim3 grid((G + 127) / 128, KFIN / 256);   // (8, 25) = 200 blocks
        k_final_mfma<256, 32><<<grid, 256, 0, stream>>>(emb, Bfl, out_final, G);
    }
}

// Round 11
// 339.266 us; speedup vs baseline: 1.0888x; 1.0507x over previous
//
#include <hip/hip_runtime.h>
#include <hip/hip_bf16.h>

#define F_IN 256
#define HID  128
#define SSUB 50
#define KFIN 6400   // SSUB * HID
#define NPB  256    // nodes per partition bucket (power of 2: bucket = dst >> 8)
#define BSBUF 10240 // LDS edge-buffer ints for bucket_sort (mean bucket 8192, +22σ)

typedef __attribute__((ext_vector_type(4))) float f32x4;
typedef __attribute__((ext_vector_type(8))) short bf16x8;

__device__ __forceinline__ void split_bf16(float v, short& hi, short& lo) {
    __hip_bfloat16 h = __float2bfloat16(v);
    float hf = __bfloat162float(h);
    __hip_bfloat16 l = __float2bfloat16(v - hf);   // exact residual, then RNE to bf16
    hi = __builtin_bit_cast(short, h);
    lo = __builtin_bit_cast(short, l);
}

__device__ __forceinline__ float bf2f(unsigned short u) {
    return __builtin_bit_cast(float, (unsigned)u << 16);
}

// ---------------- fused prep: wsplit(W1)+wsplit(W2)+wsplit(Wl)+bhist ----------------

// One thread per FRAGMENT (8 bf16 = 16B): reads 8 W elements, stores hi/lo as
// single 16B coalesced vector stores.
template<int K>
__device__ __forceinline__ void wsplit_body(const float* __restrict__ W,
                                            short* __restrict__ Bf, int blk) {
    constexpr int NF = (K / 32) * 8 * 64;   // fragments
    int f = blk * 256 + threadIdx.x;
    if (f >= NF) return;
    int lane = f & 63;
    int nt = (f >> 6) & 7;
    int kc = f >> 9;
    int quad = lane >> 4, nc = lane & 15;
    int n = nt * 16 + nc;
    int k0 = kc * 32 + quad * 8;
    bf16x8 hi8, lo8;
#pragma unroll
    for (int j = 0; j < 8; ++j) {
        short hi, lo;
        split_bf16(W[(size_t)(k0 + j) * HID + n], hi, lo);
        hi8[j] = hi; lo8[j] = lo;
    }
    ((bf16x8*)Bf)[f] = hi8;
    ((bf16x8*)(Bf + (size_t)K * HID))[f] = lo8;
}

__device__ __forceinline__ void bhist_body(const int* __restrict__ dst,
                                           int* __restrict__ bcnt,
                                           int E, int blk, int nbh) {
    __shared__ int lcnt[256];
    int tid = threadIdx.x;
    lcnt[tid] = 0;
    __syncthreads();
    int n4 = E >> 2;
    int stride = nbh * 256;
    for (int i = blk * 256 + tid; i < n4; i += stride) {
        int4 d = ((const int4*)dst)[i];
        atomicAdd(&lcnt[d.x >> 8], 1);
        atomicAdd(&lcnt[d.y >> 8], 1);
        atomicAdd(&lcnt[d.z >> 8], 1);
        atomicAdd(&lcnt[d.w >> 8], 1);
    }
    if (blk == 0) {
        for (int e = (n4 << 2) + tid; e < E; e += 256)
            atomicAdd(&lcnt[dst[e] >> 8], 1);
    }
    __syncthreads();
    if (lcnt[tid]) atomicAdd(&bcnt[tid], lcnt[tid]);
}

__global__ __launch_bounds__(256) void k_prep(const float* __restrict__ W1, short* __restrict__ Bf1,
                                              const float* __restrict__ W2, short* __restrict__ Bf2,
                                              const float* __restrict__ Wl, short* __restrict__ Bfl,
                                              const int* __restrict__ dst, int* __restrict__ bcnt,
                                              int E, int nb1, int nb2, int nbl, int nbh) {
    int b = blockIdx.x;
    if (b < nb1) { wsplit_body<F_IN>(W1, Bf1, b); return; }
    b -= nb1;
    if (b < nb2) { wsplit_body<HID>(W2, Bf2, b); return; }
    b -= nb2;
    if (b < nbl) { wsplit_body<KFIN>(Wl, Bfl, b); return; }
    b -= nbl;
    bhist_body(dst, bcnt, E, b, nbh);
}

// exclusive scan of 256 bucket counts -> bbase[0..256]; bcursor = copy for partition
__global__ void k_bscan(const int* __restrict__ bcnt, int* __restrict__ bbase,
                        int* __restrict__ bcursor) {
    __shared__ int buf[256];
    int tid = threadIdx.x;
    int v = bcnt[tid];
    buf[tid] = v;
    __syncthreads();
    for (int off = 1; off < 256; off <<= 1) {
        int t = (tid >= off) ? buf[tid - off] : 0;
        __syncthreads();
        buf[tid] += t;
        __syncthreads();
    }
    int ex = buf[tid] - v;
    bbase[tid] = ex;
    bcursor[tid] = ex;
    if (tid == 255) bbase[256] = buf[255];
}

// ---- partition edges into coarse buckets (dst>>8), block-batched append ----
__global__ __launch_bounds__(256) void k_partition(const int* __restrict__ src,
                                                   const int* __restrict__ dst,
                                                   int* __restrict__ bcursor,
                                                   int* __restrict__ part, int E) {
    __shared__ int lcnt[256];
    __shared__ int lbase[256];
    int tid = threadIdx.x;
    lcnt[tid] = 0;
    __syncthreads();
    int base = blockIdx.x * 4096;
    int pp[16], rb[16];
#pragma unroll
    for (int i = 0; i < 16; ++i) {
        int e = base + i * 256 + tid;
        int pv = 0, pk = 0;
        if (e < E) {
            int s = src[e];
            int d = dst[e];
            int b = d >> 8;                     // NPB = 256
            int r = atomicAdd(&lcnt[b], 1);     // r < 4096
            pk = (r << 8) | b;
            pv = (s << 8) | (d & 255);
        }
        pp[i] = pv; rb[i] = pk;
    }
    __syncthreads();
    lbase[tid] = lcnt[tid] ? atomicAdd(&bcursor[tid], lcnt[tid]) : 0;
    __syncthreads();
#pragma unroll
    for (int i = 0; i < 16; ++i) {
        int e = base + i * 256 + tid;
        if (e < E) {
            int b = rb[i] & 255;
            int r = rb[i] >> 8;
            part[(size_t)(lbase[b] + r)] = pp[i];
        }
    }
}

// ---- per-bucket counting sort with LDS-staged edge slice ----
__global__ __launch_bounds__(512) void k_bucket_sort(const int* __restrict__ part,
                                                     const int* __restrict__ bbase,
                                                     int* __restrict__ row_ptr,
                                                     float* __restrict__ dinv,
                                                     int* __restrict__ csr_src,
                                                     int N, int E) {
    __shared__ int lcnt[256];
    __shared__ int lcur[256];
    __shared__ int sbuf[256];
    __shared__ int ebuf[BSBUF];
    int tid = threadIdx.x;
    int b = blockIdx.x;
    int beg = bbase[b], end = bbase[b + 1];
    int cnt = end - beg;
    int lim = cnt < BSBUF ? cnt : BSBUF;
    for (int k = tid; k < lim; k += 512)
        ebuf[k] = part[beg + k];
    if (tid < 256) lcnt[tid] = 0;
    __syncthreads();
    for (int k = tid; k < lim; k += 512)
        atomicAdd(&lcnt[ebuf[k] & (NPB - 1)], 1);
    for (int k = BSBUF + tid; k < cnt; k += 512)
        atomicAdd(&lcnt[part[beg + k] & (NPB - 1)], 1);
    __syncthreads();
    int v = (tid < 256) ? lcnt[tid] : 0;
    if (tid < 256) sbuf[tid] = v;
    __syncthreads();
    for (int off = 1; off < 256; off <<= 1) {
        int t = (tid >= off && tid < 256) ? sbuf[tid - off] : 0;
        __syncthreads();
        if (tid < 256) sbuf[tid] += t;
        __syncthreads();
    }
    if (tid < 256) {
        int loff = sbuf[tid] - v;        // exclusive within-bucket offset
        lcur[tid] = beg + loff;
        int node = b * NPB + tid;
        if (node < N) {
            row_ptr[node] = beg + loff;
            dinv[node] = rsqrtf((float)(v + 1));   // +1 self loop
        }
        if (node == 0) row_ptr[N] = E;
    }
    __syncthreads();
    for (int k = tid; k < lim; k += 512) {
        int p = ebuf[k];
        int pos = atomicAdd(&lcur[p & (NPB - 1)], 1);
        csr_src[pos] = p >> 8;
    }
    for (int k = BSBUF + tid; k < cnt; k += 512) {
        int p = part[beg + k];
        int pos = atomicAdd(&lcur[p & (NPB - 1)], 1);
        csr_src[pos] = p >> 8;
    }
}

// ---------------- MFMA GEMM: Cb(MxHID, bf16) = (A(MxK, fp32) @ W) * dinv[row] ----------------
// LDS-staged B: per kc, the 16KB B panel (hi+lo) is staged ONCE per 8-wave block
// (128 rows) instead of re-read from L2 by every wave. B L2 traffic: 400->51 MB.
// B fragments read from LDS at point of use (consecutive-16B-per-lane =
// conflict-free); no bh[8]/bl[8] register arrays -> low VGPR, high occupancy.
// B(kc+1) and A(kc+1) register-prefetched during compute to hide global latency.
template<int K>
__global__ __launch_bounds__(512) void k_gemm_mfma(const float* __restrict__ A,
                                                   const short* __restrict__ Bf,
                                                   const float* __restrict__ dinv,
                                                   unsigned short* __restrict__ Cb, int M) {
    constexpr int KC = K / 32;
    __shared__ bf16x8 LBH[512];   // 8KB: hi fragments of current kc
    __shared__ bf16x8 LBL[512];   // 8KB: lo fragments of current kc
    int tid = threadIdx.x;
    int base = blockIdx.x * 128;  // 8 waves x 16 rows
    int lane = tid & 63;
    int w = tid >> 6;
    int quad = lane >> 4;
    int mrow = base + w * 16 + (lane & 15);
    bool valid = (mrow < M);
    const float* arow = A + (size_t)mrow * K;
    f32x4 acc[8] = {};
    const bf16x8* BfH = (const bf16x8*)Bf;
    const bf16x8* BfL = (const bf16x8*)(Bf + (size_t)K * HID);

    // prefetch kc=0: B fragment (1 per thread) + this lane's A window
    bf16x8 pH = BfH[tid];
    bf16x8 pL = BfL[tid];
    f32x4 pa0 = {0.f, 0.f, 0.f, 0.f};
    f32x4 pa1 = {0.f, 0.f, 0.f, 0.f};
    if (valid) {
        pa0 = *(const f32x4*)(arow + quad * 8);
        pa1 = *(const f32x4*)(arow + quad * 8 + 4);
    }

    for (int kc = 0; kc < KC; ++kc) {
        __syncthreads();              // previous compute done reading LDS
        LBH[tid] = pH;
        LBL[tid] = pL;
        __syncthreads();              // staged panel visible
        // prefetch next kc (latency hides under compute below)
        if (kc + 1 < KC) {
            pH = BfH[(size_t)(kc + 1) * 512 + tid];
            pL = BfL[(size_t)(kc + 1) * 512 + tid];
        }
        f32x4 a0 = pa0, a1 = pa1;
        if (kc + 1 < KC && valid) {
            pa0 = *(const f32x4*)(arow + (kc + 1) * 32 + quad * 8);
            pa1 = *(const f32x4*)(arow + (kc + 1) * 32 + quad * 8 + 4);
        }
        bf16x8 ahi, alo;
#pragma unroll
        for (int j2 = 0; j2 < 4; ++j2) {
            short hi, lo;
            split_bf16(a0[j2], hi, lo);
            ahi[j2] = hi; alo[j2] = lo;
            split_bf16(a1[j2], hi, lo);
            ahi[4 + j2] = hi; alo[4 + j2] = lo;
        }
#pragma unroll
        for (int nt = 0; nt < 8; ++nt) {
            bf16x8 bh = LBH[nt * 64 + lane];
            bf16x8 bl = LBL[nt * 64 + lane];
            acc[nt] = __builtin_amdgcn_mfma_f32_16x16x32_bf16(ahi, bh, acc[nt], 0, 0, 0);
            acc[nt] = __builtin_amdgcn_mfma_f32_16x16x32_bf16(alo, bh, acc[nt], 0, 0, 0);
            acc[nt] = __builtin_amdgcn_mfma_f32_16x16x32_bf16(ahi, bl, acc[nt], 0, 0, 0);
        }
    }

    // epilogue: scale row by dinv[m], quantize to bf16 (RNE)
    int mbase = base + w * 16 + quad * 4;
    int ncol = lane & 15;
    float dsc[4];
#pragma unroll
    for (int r = 0; r < 4; ++r)
        dsc[r] = (mbase + r < M) ? dinv[mbase + r] : 0.f;
#pragma unroll
    for (int nt = 0; nt < 8; ++nt) {
#pragma unroll
        for (int r = 0; r < 4; ++r) {
            int m = mbase + r;
            if (m < M) {
                __hip_bfloat16 b = __float2bfloat16(acc[nt][r] * dsc[r]);
                Cb[(size_t)m * HID + nt * 16 + ncol] = __builtin_bit_cast(unsigned short, b);
            }
        }
    }
}

// ---------------- CSR aggregation over bf16 gather buffer ----------------
__global__ __launch_bounds__(256) void k_agg(const unsigned short* __restrict__ hs,
                                             const int* __restrict__ row_ptr,
                                             const int* __restrict__ csr_src,
                                             const float* __restrict__ dinv,
                                             const float* __restrict__ bias,
                                             float* __restrict__ out, int relu, int M) {
    int n = blockIdx.x * 4 + (threadIdx.x >> 6);   // one wave per node
    if (n >= M) return;
    int lane = threadIdx.x & 63;
    int e4 = lane >> 4;       // edge sub-group 0..3
    int t  = lane & 15;       // feature group: 8 bf16 = 16B per lane

    int beg = row_ptr[n];
    int end = row_ptr[n + 1];

    float acc[8] = {0.f, 0.f, 0.f, 0.f, 0.f, 0.f, 0.f, 0.f};
    if (e4 == 0) {
        // self loop (hs pre-scaled by dinv[src])
        bf16x8 v = *(const bf16x8*)(hs + (size_t)n * HID + t * 8);
#pragma unroll
        for (int j = 0; j < 8; ++j) acc[j] = bf2f((unsigned short)v[j]);
    }

    int k = beg + e4;
    for (; k + 12 < end; k += 16) {
        int s0 = csr_src[k];
        int s1 = csr_src[k + 4];
        int s2 = csr_src[k + 8];
        int s3 = csr_src[k + 12];
        bf16x8 v0 = *(const bf16x8*)(hs + (size_t)s0 * HID + t * 8);
        bf16x8 v1 = *(const bf16x8*)(hs + (size_t)s1 * HID + t * 8);
        bf16x8 v2 = *(const bf16x8*)(hs + (size_t)s2 * HID + t * 8);
        bf16x8 v3 = *(const bf16x8*)(hs + (size_t)s3 * HID + t * 8);
#pragma unroll
        for (int j = 0; j < 8; ++j)
            acc[j] += (bf2f((unsigned short)v0[j]) + bf2f((unsigned short)v1[j]))
                    + (bf2f((unsigned short)v2[j]) + bf2f((unsigned short)v3[j]));
    }
    for (; k + 4 < end; k += 8) {
        int s0 = csr_src[k];
        int s1 = csr_src[k + 4];
        bf16x8 v0 = *(const bf16x8*)(hs + (size_t)s0 * HID + t * 8);
        bf16x8 v1 = *(const bf16x8*)(hs + (size_t)s1 * HID + t * 8);
#pragma unroll
        for (int j = 0; j < 8; ++j)
            acc[j] += bf2f((unsigned short)v0[j]) + bf2f((unsigned short)v1[j]);
    }
    if (k < end) {
        int s0 = csr_src[k];
        bf16x8 v0 = *(const bf16x8*)(hs + (size_t)s0 * HID + t * 8);
#pragma unroll
        for (int j = 0; j < 8; ++j)
            acc[j] += bf2f((unsigned short)v0[j]);
    }

    // reduce the 4 e4-groups (lanes differing in bits 4,5)
#pragma unroll
    for (int j = 0; j < 8; ++j) acc[j] += __shfl_xor(acc[j], 16, 64);
#pragma unroll
    for (int j = 0; j < 8; ++j) acc[j] += __shfl_xor(acc[j], 32, 64);

    if (e4 == 0) {
        float d = dinv[n];
        f32x4 o0, o1;
#pragma unroll
        for (int j = 0; j < 4; ++j) {
            float a = acc[j] * d + bias[t * 8 + j];
            if (relu) a = fmaxf(a, 0.f);
            o0[j] = a;
        }
#pragma unroll
        for (int j = 0; j < 4; ++j) {
            float a = acc[4 + j] * d + bias[t * 8 + 4 + j];
            if (relu) a = fmaxf(a, 0.f);
            o1[j] = a;
        }
        *(f32x4*)(out + (size_t)n * HID + t * 8)     = o0;
        *(f32x4*)(out + (size_t)n * HID + t * 8 + 4) = o1;
    }
}

// ---------------- final linear: out = pooled @ Wl + bl (MFMA, split-K) ----------------
__global__ void k_final_init(const float* __restrict__ bl, float* __restrict__ out, int total) {
    int t = blockIdx.x * blockDim.x + threadIdx.x;
    if (t < total) out[t] = bl[t & (HID - 1)];
}

template<int KS, int TILE>
__global__ __launch_bounds__(256) void k_final_mfma(const float* __restrict__ emb,
                                                    const short* __restrict__ Bf,
                                                    float* __restrict__ out, int M) {
    constexpr int BM = 128;
    constexpr int LDA = TILE + 4;
    __shared__ float As[BM * LDA];
    int tid = threadIdx.x;
    int g0 = blockIdx.x * BM;
    int k0 = blockIdx.y * KS;
    int lane = tid & 63;
    int w = tid >> 6;
    int quad = lane >> 4;
    f32x4 acc[2][8] = {};
    const bf16x8* BfH = (const bf16x8*)Bf;
    const bf16x8* BfL = (const bf16x8*)(Bf + (size_t)KFIN * HID);

    for (int t = 0; t < KS / TILE; ++t) {
        __syncthreads();
        constexpr int ITERS = (BM * (TILE / 4)) / 256;
#pragma unroll
        for (int i = 0; i < ITERS; ++i) {
            int f4 = tid + i * 256;
            int row = f4 / (TILE / 4);
            int c4 = f4 % (TILE / 4);
            f32x4 v = {0.f, 0.f, 0.f, 0.f};
            int m = g0 + row;
            if (m < M) v = *(const f32x4*)(emb + (size_t)m * KFIN + k0 + t * TILE + c4 * 4);
            *(f32x4*)(&As[row * LDA + c4 * 4]) = v;
        }
        __syncthreads();
        for (int kc = 0; kc < TILE / 32; ++kc) {
            int kcg = (k0 + t * TILE) / 32 + kc;
            bf16x8 bh[8], bl[8];
            size_t boff = (size_t)kcg * 8 * 64 + lane;
#pragma unroll
            for (int nt = 0; nt < 8; ++nt) {
                bh[nt] = BfH[boff + (size_t)nt * 64];
                bl[nt] = BfL[boff + (size_t)nt * 64];
            }
#pragma unroll
            for (int f = 0; f < 2; ++f) {
                int mrow = w * 32 + f * 16 + (lane & 15);
                const float* ap = &As[mrow * LDA + kc * 32 + quad * 8];
                f32x4 a0 = *(const f32x4*)ap;
                f32x4 a1 = *(const f32x4*)(ap + 4);
                bf16x8 ahi, alo;
#pragma unroll
                for (int j2 = 0; j2 < 4; ++j2) {
                    short hi, lo;
                    split_bf16(a0[j2], hi, lo);
                    ahi[j2] = hi; alo[j2] = lo;
                    split_bf16(a1[j2], hi, lo);
                    ahi[4 + j2] = hi; alo[4 + j2] = lo;
                }
#pragma unroll
                for (int nt = 0; nt < 8; ++nt) {
                    acc[f][nt] = __builtin_amdgcn_mfma_f32_16x16x32_bf16(ahi, bh[nt], acc[f][nt], 0, 0, 0);
                    acc[f][nt] = __builtin_amdgcn_mfma_f32_16x16x32_bf16(alo, bh[nt], acc[f][nt], 0, 0, 0);
                    acc[f][nt] = __builtin_amdgcn_mfma_f32_16x16x32_bf16(ahi, bl[nt], acc[f][nt], 0, 0, 0);
                }
            }
        }
    }

    int ncol = lane & 15;
#pragma unroll
    for (int f = 0; f < 2; ++f) {
        int mbase = g0 + w * 32 + f * 16 + quad * 4;
#pragma unroll
        for (int nt = 0; nt < 8; ++nt) {
#pragma unroll
            for (int r = 0; r < 4; ++r) {
                int m = mbase + r;
                if (m < M) atomicAdd(&out[(size_t)m * HID + nt * 16 + ncol], acc[f][nt][r]);
            }
        }
    }
}

extern "C" void kernel_launch(void* const* d_in, const int* in_sizes, int n_in,
                              void* d_out, int out_size, void* d_ws, size_t ws_size,
                              hipStream_t stream) {
    const float* x  = (const float*)d_in[0];
    const float* W1 = (const float*)d_in[1];
    const float* b1 = (const float*)d_in[2];
    const float* W2 = (const float*)d_in[3];
    const float* b2 = (const float*)d_in[4];
    const float* Wl = (const float*)d_in[5];
    const float* bl = (const float*)d_in[6];
    const int* edge = (const int*)d_in[7];

    const int N = in_sizes[0] / F_IN;       // 50000
    const int E = in_sizes[7] / 2;          // 1600000
    const int G = N / SSUB;                 // 1000
    const int NH = N * HID;
    const int nbkt = (N + NPB - 1) / NPB;   // 196 coarse buckets

    const int* src = edge;
    const int* dst = edge + E;

    // workspace layout
    char* ws = (char*)d_ws;
    float* dinv    = (float*)ws;                 ws += (size_t)N * 4;
    int*   row_ptr = (int*)ws;                   ws += (size_t)(N + 64) * 4;
    int*   bcnt    = (int*)ws;                   ws += (size_t)256 * 4;
    int*   bbase   = (int*)ws;                   ws += (size_t)320 * 4;
    int*   bcursor = (int*)ws;                   ws += (size_t)256 * 4;
    int*   csr_src = (int*)ws;                   ws += (size_t)E * 4;
    int*   part    = (int*)ws;                   ws += (size_t)E * 4;   // packed (src<<8|dst&255)
    unsigned short* hs0 = (unsigned short*)ws;   ws += (size_t)NH * 2;  // bf16 gather buf L1
    unsigned short* hs1 = (unsigned short*)ws;   ws += (size_t)NH * 2;  // bf16 gather buf L2
    float* h       = (float*)ws;                 ws += (size_t)NH * 4;  // fp32 relu'd hidden
    short* Bf1     = (short*)ws;                 ws += (size_t)2 * F_IN * HID * 2;  // hi+lo bf16
    short* Bf2     = (short*)ws;                 ws += (size_t)2 * HID * HID * 2;
    short* Bfl     = (short*)ws;                 ws += (size_t)2 * KFIN * HID * 2;

    float* out_final = (float*)d_out;                 // G*H
    float* emb       = out_final + (size_t)G * HID;   // N*H

    // ---- fused prep (wsplit x3, fragment-per-thread + bucket histogram) ----
    hipMemsetAsync(bcnt, 0, 256 * sizeof(int), stream);
    {
        const int nb1 = ((F_IN / 32) * 8 * 64 + 255) / 256;   // 16
        const int nb2 = ((HID  / 32) * 8 * 64 + 255) / 256;   // 8
        const int nbl = ((KFIN / 32) * 8 * 64 + 255) / 256;   // 400
        const int nbh = ((E >> 2) + 255) / 256;               // 1563
        k_prep<<<nb1 + nb2 + nbl + nbh, 256, 0, stream>>>(W1, Bf1, W2, Bf2, Wl, Bfl,
                                                          dst, bcnt, E, nb1, nb2, nbl, nbh);
    }
    k_bscan<<<1, 256, 0, stream>>>(bcnt, bbase, bcursor);
    k_partition<<<(E + 4095) / 4096, 256, 0, stream>>>(src, dst, bcursor, part, E);
    k_bucket_sort<<<nbkt, 512, 0, stream>>>(part, bbase, row_ptr, dinv, csr_src, N, E);

    // ---- layer 1 ----
    k_gemm_mfma<F_IN><<<(N + 127) / 128, 512, 0, stream>>>(x, Bf1, dinv, hs0, N);  // hs0 = bf16((x@W1)*dinv)
    k_agg<<<(N + 3) / 4, 256, 0, stream>>>(hs0, row_ptr, csr_src, dinv, b1, h, 1, N);

    // ---- layer 2 ----
    k_gemm_mfma<HID><<<(N + 127) / 128, 512, 0, stream>>>(h, Bf2, dinv, hs1, N);   // hs1 = bf16((h@W2)*dinv)
    k_agg<<<(N + 3) / 4, 256, 0, stream>>>(hs1, row_ptr, csr_src, dinv, b2, emb, 0, N);

    // ---- final linear (bias init + MFMA split-K accumulate, BM=128, 25 K-slices) ----
    k_final_init<<<(G * HID + 255) / 256, 256, 0, stream>>>(bl, out_final, G * HID);
    {
        dim3 grid((G + 127) / 128, KFIN / 256);   // (8, 25) = 200 blocks
        k_final_mfma<256, 32><<<grid, 256, 0, stream>>>(emb, Bfl, out_final, G);
    }
}